// Round 5
// baseline (402.913 us; speedup 1.0000x reference)
//
#include <hip/hip_runtime.h>
#include <cstdint>
#include <cstddef>

#define NN 50000
#define EE 500000
#define RR 8
#define CC 128
#define BB 4
#define H3C 384
#define NSLOT 9
#define NCOL 1152  // NSLOT * CC
#define NT 18      // NCOL / 64 column tiles
#define NB 196     // ceil(NN/256)

typedef unsigned short ushort_t;
typedef __bf16 bf16x8 __attribute__((ext_vector_type(8)));
typedef float f32x4 __attribute__((ext_vector_type(4)));
typedef unsigned short u16x8 __attribute__((ext_vector_type(8)));

static __device__ __forceinline__ ushort_t f2bf(float f) {
  unsigned u = __float_as_uint(f);
  unsigned r = (u + 0x7fffu + ((u >> 16) & 1u)) >> 16;
  return (ushort_t)r;
}
static __device__ __forceinline__ float bf2f(ushort_t u) {
  return __uint_as_float(((unsigned)u) << 16);
}

__global__ void zero_int_k(int* p, int n) {
  int i = blockIdx.x * 256 + threadIdx.x;
  if (i < n) p[i] = 0;
}

__global__ void count_k(const int* __restrict__ ei, const int* __restrict__ et, int* cnt) {
  int e = blockIdx.x * 256 + threadIdx.x;
  if (e >= EE) return;
  int d = ei[EE + e];
  int r = et[e];
  atomicAdd(&cnt[r * NN + d], 1);
}

// Block-level exclusive scan of per-node degree (sum of per-relation counts).
__global__ __launch_bounds__(256) void scanA_k(const int* __restrict__ cnt_rd, int* off, int* bsum) {
  __shared__ int s[256];
  int t = threadIdx.x;
  int i = blockIdx.x * 256 + t;
  int v = 0;
  if (i < NN) {
#pragma unroll
    for (int r = 0; r < RR; ++r) v += cnt_rd[r * NN + i];
  }
  s[t] = v;
  __syncthreads();
  for (int d = 1; d < 256; d <<= 1) {
    int x = (t >= d) ? s[t - d] : 0;
    __syncthreads();
    s[t] += x;
    __syncthreads();
  }
  if (i < NN) off[i] = s[t] - v;
  if (t == 255) bsum[blockIdx.x] = s[255];
}

__global__ __launch_bounds__(256) void scanB_k(const int* __restrict__ bsum, int* bbase) {
  __shared__ int s[256];
  int t = threadIdx.x;
  int v = (t < NB) ? bsum[t] : 0;
  s[t] = v;
  __syncthreads();
  for (int d = 1; d < 256; d <<= 1) {
    int x = (t >= d) ? s[t - d] : 0;
    __syncthreads();
    s[t] += x;
    __syncthreads();
  }
  if (t < NB) bbase[t] = s[t] - v;
}

__global__ void scanC_k(int* off, const int* __restrict__ bbase) {
  int i = blockIdx.x * 256 + threadIdx.x;
  if (i < NN) off[i] += bbase[i >> 8];
  if (i == 0) off[NN] = EE;
}

// Scatter edges into CSR slots; payload = {src | (r<<20), bits(1/max(cnt_rd,1))}.
__global__ void fill_k(const int* __restrict__ ei, const int* __restrict__ et,
                       const int* __restrict__ cnt_rd, const int* __restrict__ off,
                       int* cur, uint2* __restrict__ payload) {
  int e = blockIdx.x * 256 + threadIdx.x;
  if (e >= EE) return;
  int s = ei[e], d = ei[EE + e], r = et[e];
  int pos = off[d] + atomicAdd(&cur[d], 1);
  float w = 1.0f / (float)max(cnt_rd[r * NN + d], 1);
  payload[pos] = make_uint2((unsigned)s | ((unsigned)r << 20), __float_as_uint(w));
}

// hr1[r][n][c] = bf16( sum_b comp1[r][b] * basis1[b][n][c] )
__global__ void makehr1_k(const float* __restrict__ basis1, const float* __restrict__ comp1,
                          ushort_t* __restrict__ hr) {
  int i = blockIdx.x * 256 + threadIdx.x;
  if (i >= NN * CC) return;
  const size_t st = (size_t)NN * CC;
  float b0 = basis1[i], b1 = basis1[st + i], b2 = basis1[2 * st + i], b3 = basis1[3 * st + i];
#pragma unroll
  for (int r = 0; r < RR; ++r) {
    float v = comp1[r * BB + 0] * b0 + comp1[r * BB + 1] * b1
            + comp1[r * BB + 2] * b2 + comp1[r * BB + 3] * b3;
    hr[(size_t)r * st + i] = f2bf(v);
  }
}

// Per-destination aggregation: one wave per node; half-wave 0 handles even
// edges, half-wave 1 odd edges; lane handles 4 channels (8B gather).
__global__ __launch_bounds__(256) void aggr_k(const int* __restrict__ off,
                                              const uint2* __restrict__ payload,
                                              const ushort_t* __restrict__ hr,
                                              const float* __restrict__ rootsrc,
                                              const float* __restrict__ bias,
                                              float* __restrict__ h3, int hoff,
                                              ushort_t* xb, int xoff) {
  int wave = threadIdx.x >> 6, lane = threadIdx.x & 63;
  int d = blockIdx.x * 4 + wave;
  if (d >= NN) return;
  int beg = off[d], end = off[d + 1];
  int half = lane >> 5, l = lane & 31;
  float a0 = 0.f, a1 = 0.f, a2 = 0.f, a3 = 0.f;
  for (int i = beg + half; i < end; i += 2) {
    uint2 p = payload[i];
    const ushort_t* row = hr + ((size_t)(p.x >> 20) * NN + (p.x & 0xFFFFFu)) * CC + l * 4;
    uint2 v = *(const uint2*)row;
    float w = __uint_as_float(p.y);
    a0 += w * bf2f((ushort_t)(v.x & 0xFFFFu));
    a1 += w * bf2f((ushort_t)(v.x >> 16));
    a2 += w * bf2f((ushort_t)(v.y & 0xFFFFu));
    a3 += w * bf2f((ushort_t)(v.y >> 16));
  }
  a0 += __shfl_xor(a0, 32);
  a1 += __shfl_xor(a1, 32);
  a2 += __shfl_xor(a2, 32);
  a3 += __shfl_xor(a3, 32);
  if (half == 0) {
    int c = l * 4;
    float4 rt = *(const float4*)(rootsrc + (size_t)d * CC + c);
    float4 bs = *(const float4*)(bias + c);
    float v0 = fmaxf(a0 + rt.x + bs.x, 0.f);
    float v1 = fmaxf(a1 + rt.y + bs.y, 0.f);
    float v2 = fmaxf(a2 + rt.z + bs.z, 0.f);
    float v3 = fmaxf(a3 + rt.w + bs.w, 0.f);
    *(float4*)(h3 + (size_t)d * H3C + hoff + c) = make_float4(v0, v1, v2, v3);
    if (xb) {
      ushort_t pk[4] = {f2bf(v0), f2bf(v1), f2bf(v2), f2bf(v3)};
      *(uint2*)(xb + (size_t)d * 256 + xoff + c) = *(const uint2*)pk;
    }
  }
}

// Layer-3 aggregation with fused log_softmax over all 384 channels (2ch/lane).
__global__ __launch_bounds__(256) void aggr_sm_k(const int* __restrict__ off,
                                                 const uint2* __restrict__ payload,
                                                 const ushort_t* __restrict__ hr,
                                                 const float* __restrict__ rootsrc,
                                                 const float* __restrict__ bias,
                                                 float* __restrict__ h3) {
  int wave = threadIdx.x >> 6, lane = threadIdx.x & 63;
  int d = blockIdx.x * 4 + wave;
  if (d >= NN) return;
  int beg = off[d], end = off[d + 1];
  float a0 = 0.f, a1 = 0.f;
  int i = beg;
  for (; i + 1 < end; i += 2) {
    uint2 p0 = payload[i], p1 = payload[i + 1];
    unsigned v0 = *(const unsigned*)(hr + ((size_t)(p0.x >> 20) * NN + (p0.x & 0xFFFFFu)) * CC + lane * 2);
    unsigned v1 = *(const unsigned*)(hr + ((size_t)(p1.x >> 20) * NN + (p1.x & 0xFFFFFu)) * CC + lane * 2);
    float w0 = __uint_as_float(p0.y), w1 = __uint_as_float(p1.y);
    a0 += w0 * bf2f((ushort_t)(v0 & 0xFFFFu));
    a1 += w0 * bf2f((ushort_t)(v0 >> 16));
    a0 += w1 * bf2f((ushort_t)(v1 & 0xFFFFu));
    a1 += w1 * bf2f((ushort_t)(v1 >> 16));
  }
  if (i < end) {
    uint2 p0 = payload[i];
    unsigned v0 = *(const unsigned*)(hr + ((size_t)(p0.x >> 20) * NN + (p0.x & 0xFFFFFu)) * CC + lane * 2);
    float w0 = __uint_as_float(p0.y);
    a0 += w0 * bf2f((ushort_t)(v0 & 0xFFFFu));
    a1 += w0 * bf2f((ushort_t)(v0 >> 16));
  }
  int c = lane * 2;
  float v0 = fmaxf(a0 + rootsrc[(size_t)d * CC + c] + bias[c], 0.f);
  float v1 = fmaxf(a1 + rootsrc[(size_t)d * CC + c + 1] + bias[c + 1], 0.f);
  float* row = h3 + (size_t)d * H3C;
  float vals[6];
  vals[0] = row[lane];
  vals[1] = row[lane + 64];
  vals[2] = row[lane + 128];
  vals[3] = row[lane + 192];
  int s4 = lane >> 1;
  float e0 = __shfl(v0, s4), e1 = __shfl(v1, s4);
  vals[4] = (lane & 1) ? e1 : e0;
  int s5 = 32 + (lane >> 1);
  float g0 = __shfl(v0, s5), g1 = __shfl(v1, s5);
  vals[5] = (lane & 1) ? g1 : g0;
  float m = -1e30f;
#pragma unroll
  for (int j = 0; j < 6; ++j) m = fmaxf(m, vals[j]);
#pragma unroll
  for (int o = 32; o > 0; o >>= 1) m = fmaxf(m, __shfl_xor(m, o));
  float s = 0.f;
#pragma unroll
  for (int j = 0; j < 6; ++j) s += expf(vals[j] - m);
#pragma unroll
  for (int o = 32; o > 0; o >>= 1) s += __shfl_xor(s, o);
  float ls = logf(s);
#pragma unroll
  for (int j = 0; j < 6; ++j) row[lane + 64 * j] = vals[j] - m - ls;
}

// Fragment-major stacked weights:
// Wt[((ct*(K/32) + kk)*256 + cb*64 + lane)*8 + j] = W[kk*32 + (lane>>4)*8 + j][ct*64 + cb*16 + (lane&15)]
__global__ void makew2_k(const float* __restrict__ basis, const float* __restrict__ comp,
                         const float* __restrict__ root, ushort_t* __restrict__ Wt, int K) {
  int f = blockIdx.x * 256 + threadIdx.x;
  int perct = (K / 32) * 256;
  int tot = NT * perct;
  if (f >= tot) return;
  int ct = f / perct, rem = f - ct * perct;
  int kk = rem >> 8, rem2 = rem & 255;
  int cb = rem2 >> 6, l = rem2 & 63;
  int fr = l & 15, fq = l >> 4;
  int gc = ct * 64 + cb * 16 + fr;
  int r = gc >> 7, c = gc & 127;
  int k0 = kk * 32 + fq * 8;
  ushort_t o[8];
#pragma unroll
  for (int j = 0; j < 8; ++j) {
    int k = k0 + j;
    float v;
    if (r < RR) {
      size_t st = (size_t)K * CC;
      size_t p = (size_t)k * CC + c;
      v = comp[r * BB + 0] * basis[p] + comp[r * BB + 1] * basis[st + p]
        + comp[r * BB + 2] * basis[2 * st + p] + comp[r * BB + 3] * basis[3 * st + p];
    } else {
      v = root[(size_t)k * CC + c];
    }
    o[j] = f2bf(v);
  }
  *(u16x8*)(Wt + (size_t)f * 8) = *(const u16x8*)o;
}

// Row-stripe GEMM, barrier-free main loop: X tile in LDS once; B-fragments
// loaded per-MFMA straight from global (fragment-major, L1/L2-broadcast).
template <int K>
__global__ __launch_bounds__(256) void gemm3_k(const ushort_t* __restrict__ Xb,
                                               const ushort_t* __restrict__ Wt,
                                               ushort_t* __restrict__ hr,
                                               float* __restrict__ aggroot) {
  constexpr int XST = K + 8;   // LDS row stride (bf16 elems)
  constexpr int SEGS = K / 8;  // u16x8 segments per X row
  __shared__ ushort_t xs[64 * XST];
  int t = threadIdx.x;
  int wave = t >> 6, lane = t & 63;
  int fr = lane & 15, fq = lane >> 4;
  int row0 = blockIdx.x * 64;

  for (int idx = t; idx < 64 * SEGS; idx += 256) {
    int row = idx / SEGS, seg = idx - row * SEGS;
    int gr = row0 + row;
    if (gr >= NN) gr = NN - 1;
    *(u16x8*)(xs + row * XST + seg * 8) = *(const u16x8*)(Xb + (size_t)gr * 256 + seg * 8);
  }
  __syncthreads();

  for (int ct = 0; ct < NT; ++ct) {
    const ushort_t* wct = Wt + (size_t)ct * (64 * K) + (size_t)lane * 8;
    f32x4 acc[4];
#pragma unroll
    for (int cb = 0; cb < 4; ++cb) acc[cb] = (f32x4){0.f, 0.f, 0.f, 0.f};
#pragma unroll
    for (int kk = 0; kk < K / 32; ++kk) {
      bf16x8 a = *(const bf16x8*)(xs + (size_t)(wave * 16 + fr) * XST + kk * 32 + fq * 8);
#pragma unroll
      for (int cb = 0; cb < 4; ++cb) {
        bf16x8 b = *(const bf16x8*)(wct + kk * 2048 + cb * 512);
        acc[cb] = __builtin_amdgcn_mfma_f32_16x16x32_bf16(a, b, acc[cb], 0, 0, 0);
      }
    }
    int r = ct >> 1;  // slot uniform per ct
#pragma unroll
    for (int cb = 0; cb < 4; ++cb) {
      int gc = ct * 64 + cb * 16 + fr;
      int c = gc & 127;
#pragma unroll
      for (int j = 0; j < 4; ++j) {
        int n = row0 + wave * 16 + fq * 4 + j;
        if (n < NN) {
          if (r < RR) hr[((size_t)r * NN + n) * CC + c] = f2bf(acc[cb][j]);
          else        aggroot[(size_t)n * CC + c] = acc[cb][j];
        }
      }
    }
  }
}

extern "C" void kernel_launch(void* const* d_in, const int* in_sizes, int n_in,
                              void* d_out, int out_size, void* d_ws, size_t ws_size,
                              hipStream_t stream) {
  const int* ei = (const int*)d_in[0];
  const int* et = (const int*)d_in[1];
  const float* basis1 = (const float*)d_in[2];
  const float* comp1 = (const float*)d_in[3];
  const float* root1 = (const float*)d_in[4];
  const float* bias1 = (const float*)d_in[5];
  const float* basis_b0 = (const float*)d_in[6];
  const float* comp_b0 = (const float*)d_in[7];
  const float* root_b0 = (const float*)d_in[8];
  const float* bias_b0 = (const float*)d_in[9];
  const float* basis_b1 = (const float*)d_in[10];
  const float* comp_b1 = (const float*)d_in[11];
  const float* root_b1 = (const float*)d_in[12];
  const float* bias_b1 = (const float*)d_in[13];
  float* out = (float*)d_out;  // [N][384] h3 storage
  char* ws = (char*)d_ws;

  uint2* payload = (uint2*)ws;                                  // E * 8B
  float* aggroot = (float*)(payload + EE);                      // N*C f32
  ushort_t* hr = (ushort_t*)(aggroot + (size_t)NN * CC);        // 8*N*C bf16
  ushort_t* xb = hr + (size_t)RR * NN * CC;                     // N*256 bf16
  ushort_t* wt = xb + (size_t)NN * 256;                         // NCOL*256 bf16
  int* cnt_rd = (int*)(wt + (size_t)NCOL * 256);                // R*N int
  int* cur = cnt_rd + (size_t)RR * NN;                          // N int
  int* off = cur + NN;                                          // N+1 int
  int* bsum = off + NN + 1;
  int* bbase = bsum + 256;
  size_t need = (size_t)((char*)(bbase + 256) - ws);
  if (ws_size < need) return;

  // --- CSR build ---
  zero_int_k<<<(RR * NN + NN + 255) / 256, 256, 0, stream>>>(cnt_rd, RR * NN + NN);
  count_k<<<(EE + 255) / 256, 256, 0, stream>>>(ei, et, cnt_rd);
  scanA_k<<<NB, 256, 0, stream>>>(cnt_rd, off, bsum);
  scanB_k<<<1, 256, 0, stream>>>(bsum, bbase);
  scanC_k<<<NB, 256, 0, stream>>>(off, bbase);
  fill_k<<<(EE + 255) / 256, 256, 0, stream>>>(ei, et, cnt_rd, off, cur, payload);

  const int NC_BLKS = (NN * CC + 255) / 256;
  const int AG_BLKS = (NN + 3) / 4;
  const int GE_BLKS = (NN + 63) / 64;  // 782

  // --- layer 1 ---
  makehr1_k<<<NC_BLKS, 256, 0, stream>>>(basis1, comp1, hr);
  aggr_k<<<AG_BLKS, 256, 0, stream>>>(off, payload, hr, root1, bias1, out, 0, xb, 0);

  // --- layer 2 (K=128) ---
  makew2_k<<<(NT * (CC / 32) * 256 + 255) / 256, 256, 0, stream>>>(basis_b0, comp_b0, root_b0, wt, CC);
  gemm3_k<128><<<GE_BLKS, 256, 0, stream>>>(xb, wt, hr, aggroot);
  aggr_k<<<AG_BLKS, 256, 0, stream>>>(off, payload, hr, aggroot, bias_b0, out, CC, xb, CC);

  // --- layer 3 (K=256) ---
  makew2_k<<<(NT * (2 * CC / 32) * 256 + 255) / 256, 256, 0, stream>>>(basis_b1, comp_b1, root_b1, wt, 2 * CC);
  gemm3_k<256><<<GE_BLKS, 256, 0, stream>>>(xb, wt, hr, aggroot);
  aggr_sm_k<<<AG_BLKS, 256, 0, stream>>>(off, payload, hr, aggroot, bias_b1, out);
}

// Round 6
// 374.427 us; speedup vs baseline: 1.0761x; 1.0761x over previous
//
#include <hip/hip_runtime.h>
#include <cstdint>
#include <cstddef>

#define NN 50000
#define EE 500000
#define RR 8
#define CC 128
#define BB 4
#define H3C 384
#define NSLOT 9
#define NCOL 1152  // NSLOT * CC
#define NT 18      // NCOL / 64 column tiles
#define NB 196     // ceil(NN/256)
#define GS 256     // gemm4 grid.x (row-tile stride)

typedef unsigned short ushort_t;
typedef __bf16 bf16x8 __attribute__((ext_vector_type(8)));
typedef float f32x4 __attribute__((ext_vector_type(4)));
typedef unsigned short u16x8 __attribute__((ext_vector_type(8)));

static __device__ __forceinline__ ushort_t f2bf(float f) {
  unsigned u = __float_as_uint(f);
  unsigned r = (u + 0x7fffu + ((u >> 16) & 1u)) >> 16;
  return (ushort_t)r;
}
static __device__ __forceinline__ float bf2f(ushort_t u) {
  return __uint_as_float(((unsigned)u) << 16);
}

__global__ void zero_int_k(int* p, int n) {
  int i = blockIdx.x * 256 + threadIdx.x;
  if (i < n) p[i] = 0;
}

__global__ void count_k(const int* __restrict__ ei, const int* __restrict__ et, int* cnt) {
  int e = blockIdx.x * 256 + threadIdx.x;
  if (e >= EE) return;
  int d = ei[EE + e];
  int r = et[e];
  atomicAdd(&cnt[r * NN + d], 1);
}

// Block-level exclusive scan of per-node degree (sum of per-relation counts).
__global__ __launch_bounds__(256) void scanA_k(const int* __restrict__ cnt_rd, int* off, int* bsum) {
  __shared__ int s[256];
  int t = threadIdx.x;
  int i = blockIdx.x * 256 + t;
  int v = 0;
  if (i < NN) {
#pragma unroll
    for (int r = 0; r < RR; ++r) v += cnt_rd[r * NN + i];
  }
  s[t] = v;
  __syncthreads();
  for (int d = 1; d < 256; d <<= 1) {
    int x = (t >= d) ? s[t - d] : 0;
    __syncthreads();
    s[t] += x;
    __syncthreads();
  }
  if (i < NN) off[i] = s[t] - v;
  if (t == 255) bsum[blockIdx.x] = s[255];
}

__global__ __launch_bounds__(256) void scanB_k(const int* __restrict__ bsum, int* bbase) {
  __shared__ int s[256];
  int t = threadIdx.x;
  int v = (t < NB) ? bsum[t] : 0;
  s[t] = v;
  __syncthreads();
  for (int d = 1; d < 256; d <<= 1) {
    int x = (t >= d) ? s[t - d] : 0;
    __syncthreads();
    s[t] += x;
    __syncthreads();
  }
  if (t < NB) bbase[t] = s[t] - v;
}

__global__ void scanC_k(int* off, const int* __restrict__ bbase) {
  int i = blockIdx.x * 256 + threadIdx.x;
  if (i < NN) off[i] += bbase[i >> 8];
  if (i == 0) off[NN] = EE;
}

// Scatter edges into CSR slots; payload = {src | (r<<20), bits(1/max(cnt_rd,1))}.
__global__ void fill_k(const int* __restrict__ ei, const int* __restrict__ et,
                       const int* __restrict__ cnt_rd, const int* __restrict__ off,
                       int* cur, uint2* __restrict__ payload) {
  int e = blockIdx.x * 256 + threadIdx.x;
  if (e >= EE) return;
  int s = ei[e], d = ei[EE + e], r = et[e];
  int pos = off[d] + atomicAdd(&cur[d], 1);
  float w = 1.0f / (float)max(cnt_rd[r * NN + d], 1);
  payload[pos] = make_uint2((unsigned)s | ((unsigned)r << 20), __float_as_uint(w));
}

// hr1[r][n][c] = bf16( sum_b comp1[r][b] * basis1[b][n][c] )
__global__ void makehr1_k(const float* __restrict__ basis1, const float* __restrict__ comp1,
                          ushort_t* __restrict__ hr) {
  int i = blockIdx.x * 256 + threadIdx.x;
  if (i >= NN * CC) return;
  const size_t st = (size_t)NN * CC;
  float b0 = basis1[i], b1 = basis1[st + i], b2 = basis1[2 * st + i], b3 = basis1[3 * st + i];
#pragma unroll
  for (int r = 0; r < RR; ++r) {
    float v = comp1[r * BB + 0] * b0 + comp1[r * BB + 1] * b1
            + comp1[r * BB + 2] * b2 + comp1[r * BB + 3] * b3;
    hr[(size_t)r * st + i] = f2bf(v);
  }
}

// Per-destination aggregation: one wave per node; half-wave 0 handles even
// edges, half-wave 1 odd edges; lane handles 4 channels (8B gather).
__global__ __launch_bounds__(256) void aggr_k(const int* __restrict__ off,
                                              const uint2* __restrict__ payload,
                                              const ushort_t* __restrict__ hr,
                                              const float* __restrict__ rootsrc,
                                              const float* __restrict__ bias,
                                              float* __restrict__ h3, int hoff,
                                              ushort_t* xb, int xoff) {
  int wave = threadIdx.x >> 6, lane = threadIdx.x & 63;
  int d = blockIdx.x * 4 + wave;
  if (d >= NN) return;
  int beg = off[d], end = off[d + 1];
  int half = lane >> 5, l = lane & 31;
  float a0 = 0.f, a1 = 0.f, a2 = 0.f, a3 = 0.f;
  for (int i = beg + half; i < end; i += 2) {
    uint2 p = payload[i];
    const ushort_t* row = hr + ((size_t)(p.x >> 20) * NN + (p.x & 0xFFFFFu)) * CC + l * 4;
    uint2 v = *(const uint2*)row;
    float w = __uint_as_float(p.y);
    a0 += w * bf2f((ushort_t)(v.x & 0xFFFFu));
    a1 += w * bf2f((ushort_t)(v.x >> 16));
    a2 += w * bf2f((ushort_t)(v.y & 0xFFFFu));
    a3 += w * bf2f((ushort_t)(v.y >> 16));
  }
  a0 += __shfl_xor(a0, 32);
  a1 += __shfl_xor(a1, 32);
  a2 += __shfl_xor(a2, 32);
  a3 += __shfl_xor(a3, 32);
  if (half == 0) {
    int c = l * 4;
    float4 rt = *(const float4*)(rootsrc + (size_t)d * CC + c);
    float4 bs = *(const float4*)(bias + c);
    float v0 = fmaxf(a0 + rt.x + bs.x, 0.f);
    float v1 = fmaxf(a1 + rt.y + bs.y, 0.f);
    float v2 = fmaxf(a2 + rt.z + bs.z, 0.f);
    float v3 = fmaxf(a3 + rt.w + bs.w, 0.f);
    *(float4*)(h3 + (size_t)d * H3C + hoff + c) = make_float4(v0, v1, v2, v3);
    if (xb) {
      ushort_t pk[4] = {f2bf(v0), f2bf(v1), f2bf(v2), f2bf(v3)};
      *(uint2*)(xb + (size_t)d * 256 + xoff + c) = *(const uint2*)pk;
    }
  }
}

// Layer-3 aggregation with fused log_softmax over all 384 channels (2ch/lane).
__global__ __launch_bounds__(256) void aggr_sm_k(const int* __restrict__ off,
                                                 const uint2* __restrict__ payload,
                                                 const ushort_t* __restrict__ hr,
                                                 const float* __restrict__ rootsrc,
                                                 const float* __restrict__ bias,
                                                 float* __restrict__ h3) {
  int wave = threadIdx.x >> 6, lane = threadIdx.x & 63;
  int d = blockIdx.x * 4 + wave;
  if (d >= NN) return;
  int beg = off[d], end = off[d + 1];
  float a0 = 0.f, a1 = 0.f;
  int i = beg;
  for (; i + 1 < end; i += 2) {
    uint2 p0 = payload[i], p1 = payload[i + 1];
    unsigned v0 = *(const unsigned*)(hr + ((size_t)(p0.x >> 20) * NN + (p0.x & 0xFFFFFu)) * CC + lane * 2);
    unsigned v1 = *(const unsigned*)(hr + ((size_t)(p1.x >> 20) * NN + (p1.x & 0xFFFFFu)) * CC + lane * 2);
    float w0 = __uint_as_float(p0.y), w1 = __uint_as_float(p1.y);
    a0 += w0 * bf2f((ushort_t)(v0 & 0xFFFFu));
    a1 += w0 * bf2f((ushort_t)(v0 >> 16));
    a0 += w1 * bf2f((ushort_t)(v1 & 0xFFFFu));
    a1 += w1 * bf2f((ushort_t)(v1 >> 16));
  }
  if (i < end) {
    uint2 p0 = payload[i];
    unsigned v0 = *(const unsigned*)(hr + ((size_t)(p0.x >> 20) * NN + (p0.x & 0xFFFFFu)) * CC + lane * 2);
    float w0 = __uint_as_float(p0.y);
    a0 += w0 * bf2f((ushort_t)(v0 & 0xFFFFu));
    a1 += w0 * bf2f((ushort_t)(v0 >> 16));
  }
  int c = lane * 2;
  float v0 = fmaxf(a0 + rootsrc[(size_t)d * CC + c] + bias[c], 0.f);
  float v1 = fmaxf(a1 + rootsrc[(size_t)d * CC + c + 1] + bias[c + 1], 0.f);
  float* row = h3 + (size_t)d * H3C;
  float vals[6];
  vals[0] = row[lane];
  vals[1] = row[lane + 64];
  vals[2] = row[lane + 128];
  vals[3] = row[lane + 192];
  int s4 = lane >> 1;
  float e0 = __shfl(v0, s4), e1 = __shfl(v1, s4);
  vals[4] = (lane & 1) ? e1 : e0;
  int s5 = 32 + (lane >> 1);
  float g0 = __shfl(v0, s5), g1 = __shfl(v1, s5);
  vals[5] = (lane & 1) ? g1 : g0;
  float m = -1e30f;
#pragma unroll
  for (int j = 0; j < 6; ++j) m = fmaxf(m, vals[j]);
#pragma unroll
  for (int o = 32; o > 0; o >>= 1) m = fmaxf(m, __shfl_xor(m, o));
  float s = 0.f;
#pragma unroll
  for (int j = 0; j < 6; ++j) s += expf(vals[j] - m);
#pragma unroll
  for (int o = 32; o > 0; o >>= 1) s += __shfl_xor(s, o);
  float ls = logf(s);
#pragma unroll
  for (int j = 0; j < 6; ++j) row[lane + 64 * j] = vals[j] - m - ls;
}

// Fragment-major stacked weights:
// Wt[((ct*(K/32) + kk)*256 + cb*64 + lane)*8 + j] = W[kk*32 + (lane>>4)*8 + j][ct*64 + cb*16 + (lane&15)]
__global__ void makew2_k(const float* __restrict__ basis, const float* __restrict__ comp,
                         const float* __restrict__ root, ushort_t* __restrict__ Wt, int K) {
  int f = blockIdx.x * 256 + threadIdx.x;
  int perct = (K / 32) * 256;
  int tot = NT * perct;
  if (f >= tot) return;
  int ct = f / perct, rem = f - ct * perct;
  int kk = rem >> 8, rem2 = rem & 255;
  int cb = rem2 >> 6, l = rem2 & 63;
  int fr = l & 15, fq = l >> 4;
  int gc = ct * 64 + cb * 16 + fr;
  int r = gc >> 7, c = gc & 127;
  int k0 = kk * 32 + fq * 8;
  ushort_t o[8];
#pragma unroll
  for (int j = 0; j < 8; ++j) {
    int k = k0 + j;
    float v;
    if (r < RR) {
      size_t st = (size_t)K * CC;
      size_t p = (size_t)k * CC + c;
      v = comp[r * BB + 0] * basis[p] + comp[r * BB + 1] * basis[st + p]
        + comp[r * BB + 2] * basis[2 * st + p] + comp[r * BB + 3] * basis[3 * st + p];
    } else {
      v = root[(size_t)k * CC + c];
    }
    o[j] = f2bf(v);
  }
  *(u16x8*)(Wt + (size_t)f * 8) = *(const u16x8*)o;
}

// One wave per block; block owns column tile ct with ALL B-fragments in
// registers; loops over 16-row tiles with A software-pipelined (aA/aB).
// No LDS, no barriers.
template <int K>
__global__ __launch_bounds__(64, 2) void gemm4_k(const ushort_t* __restrict__ Xb,
                                                 const ushort_t* __restrict__ Wt,
                                                 ushort_t* __restrict__ hr,
                                                 float* __restrict__ aggroot) {
  constexpr int KK = K / 32;       // 4 or 8
  constexpr int NTILES = NN / 16;  // 3125
  int lane = threadIdx.x;
  int fr = lane & 15, fq = lane >> 4;
  int ct = blockIdx.y;
  int r = ct >> 1;  // uniform per block

  // B fragments for this 64-col tile, resident in VGPRs for kernel lifetime.
  bf16x8 breg[KK * 4];
  {
    const ushort_t* wct = Wt + (size_t)ct * (64 * K) + (size_t)lane * 8;
#pragma unroll
    for (int kk = 0; kk < KK; ++kk)
#pragma unroll
      for (int cb = 0; cb < 4; ++cb)
        breg[kk * 4 + cb] = *(const bf16x8*)(wct + kk * 2048 + cb * 512);
  }

  bf16x8 aA[KK], aB[KK];

#define LOAD_A(dst, tt)                                                         \
  {                                                                             \
    const ushort_t* ap = Xb + ((size_t)(tt) * 16 + fr) * 256 + fq * 8;          \
    _Pragma("unroll") for (int kk = 0; kk < KK; ++kk)                           \
        dst[kk] = *(const bf16x8*)(ap + kk * 32);                               \
  }

#define COMPUTE_STORE(a, tt)                                                    \
  {                                                                             \
    f32x4 acc[4];                                                               \
    _Pragma("unroll") for (int cb = 0; cb < 4; ++cb)                            \
        acc[cb] = (f32x4){0.f, 0.f, 0.f, 0.f};                                  \
    _Pragma("unroll") for (int kk = 0; kk < KK; ++kk)                           \
        _Pragma("unroll") for (int cb = 0; cb < 4; ++cb)                        \
            acc[cb] = __builtin_amdgcn_mfma_f32_16x16x32_bf16(                  \
                a[kk], breg[kk * 4 + cb], acc[cb], 0, 0, 0);                    \
    int nb = (tt) * 16 + fq * 4;                                                \
    if (r < RR) {                                                               \
      _Pragma("unroll") for (int cb = 0; cb < 4; ++cb) {                        \
        int c = (ct * 64 + cb * 16 + fr) & 127;                                 \
        _Pragma("unroll") for (int j = 0; j < 4; ++j)                           \
            hr[((size_t)r * NN + nb + j) * CC + c] = f2bf(acc[cb][j]);          \
      }                                                                         \
    } else {                                                                    \
      _Pragma("unroll") for (int cb = 0; cb < 4; ++cb) {                        \
        int c = (ct * 64 + cb * 16 + fr) & 127;                                 \
        _Pragma("unroll") for (int j = 0; j < 4; ++j)                           \
            aggroot[(size_t)(nb + j) * CC + c] = acc[cb][j];                    \
      }                                                                         \
    }                                                                           \
  }

  int t0 = blockIdx.x;
  LOAD_A(aA, t0);
  for (int t = t0; t < NTILES; t += 2 * GS) {
    int t1 = t + GS;
    if (t1 < NTILES) LOAD_A(aB, t1);
    COMPUTE_STORE(aA, t);
    int t2 = t + 2 * GS;
    if (t2 < NTILES) LOAD_A(aA, t2);
    if (t1 < NTILES) COMPUTE_STORE(aB, t1);
  }
#undef LOAD_A
#undef COMPUTE_STORE
}

extern "C" void kernel_launch(void* const* d_in, const int* in_sizes, int n_in,
                              void* d_out, int out_size, void* d_ws, size_t ws_size,
                              hipStream_t stream) {
  const int* ei = (const int*)d_in[0];
  const int* et = (const int*)d_in[1];
  const float* basis1 = (const float*)d_in[2];
  const float* comp1 = (const float*)d_in[3];
  const float* root1 = (const float*)d_in[4];
  const float* bias1 = (const float*)d_in[5];
  const float* basis_b0 = (const float*)d_in[6];
  const float* comp_b0 = (const float*)d_in[7];
  const float* root_b0 = (const float*)d_in[8];
  const float* bias_b0 = (const float*)d_in[9];
  const float* basis_b1 = (const float*)d_in[10];
  const float* comp_b1 = (const float*)d_in[11];
  const float* root_b1 = (const float*)d_in[12];
  const float* bias_b1 = (const float*)d_in[13];
  float* out = (float*)d_out;  // [N][384] h3 storage
  char* ws = (char*)d_ws;

  uint2* payload = (uint2*)ws;                                  // E * 8B
  float* aggroot = (float*)(payload + EE);                      // N*C f32
  ushort_t* hr = (ushort_t*)(aggroot + (size_t)NN * CC);        // 8*N*C bf16
  ushort_t* xb = hr + (size_t)RR * NN * CC;                     // N*256 bf16
  ushort_t* wt = xb + (size_t)NN * 256;                         // NCOL*256 bf16
  int* cnt_rd = (int*)(wt + (size_t)NCOL * 256);                // R*N int
  int* cur = cnt_rd + (size_t)RR * NN;                          // N int
  int* off = cur + NN;                                          // N+1 int
  int* bsum = off + NN + 1;
  int* bbase = bsum + 256;
  size_t need = (size_t)((char*)(bbase + 256) - ws);
  if (ws_size < need) return;

  // --- CSR build ---
  zero_int_k<<<(RR * NN + NN + 255) / 256, 256, 0, stream>>>(cnt_rd, RR * NN + NN);
  count_k<<<(EE + 255) / 256, 256, 0, stream>>>(ei, et, cnt_rd);
  scanA_k<<<NB, 256, 0, stream>>>(cnt_rd, off, bsum);
  scanB_k<<<1, 256, 0, stream>>>(bsum, bbase);
  scanC_k<<<NB, 256, 0, stream>>>(off, bbase);
  fill_k<<<(EE + 255) / 256, 256, 0, stream>>>(ei, et, cnt_rd, off, cur, payload);

  const int NC_BLKS = (NN * CC + 255) / 256;
  const int AG_BLKS = (NN + 3) / 4;
  dim3 gg4(GS, NT);  // (256, 18), 64-thread blocks

  // --- layer 1 ---
  makehr1_k<<<NC_BLKS, 256, 0, stream>>>(basis1, comp1, hr);
  aggr_k<<<AG_BLKS, 256, 0, stream>>>(off, payload, hr, root1, bias1, out, 0, xb, 0);

  // --- layer 2 (K=128) ---
  makew2_k<<<(NT * (CC / 32) * 256 + 255) / 256, 256, 0, stream>>>(basis_b0, comp_b0, root_b0, wt, CC);
  gemm4_k<128><<<gg4, 64, 0, stream>>>(xb, wt, hr, aggroot);
  aggr_k<<<AG_BLKS, 256, 0, stream>>>(off, payload, hr, aggroot, bias_b0, out, CC, xb, CC);

  // --- layer 3 (K=256) ---
  makew2_k<<<(NT * (2 * CC / 32) * 256 + 255) / 256, 256, 0, stream>>>(basis_b1, comp_b1, root_b1, wt, 2 * CC);
  gemm4_k<256><<<gg4, 64, 0, stream>>>(xb, wt, hr, aggroot);
  aggr_sm_k<<<AG_BLKS, 256, 0, stream>>>(off, payload, hr, aggroot, bias_b1, out);
}

// Round 7
// 351.804 us; speedup vs baseline: 1.1453x; 1.0643x over previous
//
#include <hip/hip_runtime.h>
#include <cstdint>
#include <cstddef>

#define NN 50000
#define EE 500000
#define RR 8
#define CC 128
#define BB 4
#define H3C 384
#define NB 196  // ceil(NN/256)

typedef unsigned short ushort_t;
typedef __bf16 bf16x8 __attribute__((ext_vector_type(8)));
typedef float f32x4 __attribute__((ext_vector_type(4)));
typedef unsigned short u16x8 __attribute__((ext_vector_type(8)));

static __device__ __forceinline__ ushort_t f2bf(float f) {
  unsigned u = __float_as_uint(f);
  unsigned r = (u + 0x7fffu + ((u >> 16) & 1u)) >> 16;
  return (ushort_t)r;
}
static __device__ __forceinline__ float bf2f(ushort_t u) {
  return __uint_as_float(((unsigned)u) << 16);
}

__global__ void zero_int_k(int* p, int n) {
  int i = blockIdx.x * 256 + threadIdx.x;
  if (i < n) p[i] = 0;
}

__global__ void count_k(const int* __restrict__ ei, const int* __restrict__ et, int* cnt) {
  int e = blockIdx.x * 256 + threadIdx.x;
  if (e >= EE) return;
  int d = ei[EE + e];
  int r = et[e];
  atomicAdd(&cnt[r * NN + d], 1);
}

__global__ __launch_bounds__(256) void scanA_k(const int* __restrict__ cnt_rd, int* off, int* bsum) {
  __shared__ int s[256];
  int t = threadIdx.x;
  int i = blockIdx.x * 256 + t;
  int v = 0;
  if (i < NN) {
#pragma unroll
    for (int r = 0; r < RR; ++r) v += cnt_rd[r * NN + i];
  }
  s[t] = v;
  __syncthreads();
  for (int d = 1; d < 256; d <<= 1) {
    int x = (t >= d) ? s[t - d] : 0;
    __syncthreads();
    s[t] += x;
    __syncthreads();
  }
  if (i < NN) off[i] = s[t] - v;
  if (t == 255) bsum[blockIdx.x] = s[255];
}

__global__ __launch_bounds__(256) void scanB_k(const int* __restrict__ bsum, int* bbase) {
  __shared__ int s[256];
  int t = threadIdx.x;
  int v = (t < NB) ? bsum[t] : 0;
  s[t] = v;
  __syncthreads();
  for (int d = 1; d < 256; d <<= 1) {
    int x = (t >= d) ? s[t - d] : 0;
    __syncthreads();
    s[t] += x;
    __syncthreads();
  }
  if (t < NB) bbase[t] = s[t] - v;
}

__global__ void scanC_k(int* off, const int* __restrict__ bbase) {
  int i = blockIdx.x * 256 + threadIdx.x;
  if (i < NN) off[i] += bbase[i >> 8];
  if (i == 0) off[NN] = EE;
}

// Scatter edges into CSR slots; payload = {src | (r<<20), bits(1/max(cnt_rd,1))}.
__global__ void fill_k(const int* __restrict__ ei, const int* __restrict__ et,
                       const int* __restrict__ cnt_rd, const int* __restrict__ off,
                       int* cur, uint2* __restrict__ payload) {
  int e = blockIdx.x * 256 + threadIdx.x;
  if (e >= EE) return;
  int s = ei[e], d = ei[EE + e], r = et[e];
  int pos = off[d] + atomicAdd(&cur[d], 1);
  float w = 1.0f / (float)max(cnt_rd[r * NN + d], 1);
  payload[pos] = make_uint2((unsigned)s | ((unsigned)r << 20), __float_as_uint(w));
}

// hr1[r][n][c] = bf16( sum_b comp1[r][b] * basis1[b][n][c] )
__global__ void makehr1_k(const float* __restrict__ basis1, const float* __restrict__ comp1,
                          ushort_t* __restrict__ hr) {
  int i = blockIdx.x * 256 + threadIdx.x;
  if (i >= NN * CC) return;
  const size_t st = (size_t)NN * CC;
  float b0 = basis1[i], b1 = basis1[st + i], b2 = basis1[2 * st + i], b3 = basis1[3 * st + i];
#pragma unroll
  for (int r = 0; r < RR; ++r) {
    float v = comp1[r * BB + 0] * b0 + comp1[r * BB + 1] * b1
            + comp1[r * BB + 2] * b2 + comp1[r * BB + 3] * b3;
    hr[(size_t)r * st + i] = f2bf(v);
  }
}

// Layer-1 per-destination aggregation: one wave per node; half-wave edge split.
__global__ __launch_bounds__(256) void aggr_k(const int* __restrict__ off,
                                              const uint2* __restrict__ payload,
                                              const ushort_t* __restrict__ hr,
                                              const float* __restrict__ rootsrc,
                                              const float* __restrict__ bias,
                                              float* __restrict__ h3,
                                              ushort_t* __restrict__ xb) {
  int wave = threadIdx.x >> 6, lane = threadIdx.x & 63;
  int d = blockIdx.x * 4 + wave;
  if (d >= NN) return;
  int beg = off[d], end = off[d + 1];
  int half = lane >> 5, l = lane & 31;
  float a0 = 0.f, a1 = 0.f, a2 = 0.f, a3 = 0.f;
  for (int i = beg + half; i < end; i += 2) {
    uint2 p = payload[i];
    const ushort_t* row = hr + ((size_t)(p.x >> 20) * NN + (p.x & 0xFFFFFu)) * CC + l * 4;
    uint2 v = *(const uint2*)row;
    float w = __uint_as_float(p.y);
    a0 += w * bf2f((ushort_t)(v.x & 0xFFFFu));
    a1 += w * bf2f((ushort_t)(v.x >> 16));
    a2 += w * bf2f((ushort_t)(v.y & 0xFFFFu));
    a3 += w * bf2f((ushort_t)(v.y >> 16));
  }
  a0 += __shfl_xor(a0, 32);
  a1 += __shfl_xor(a1, 32);
  a2 += __shfl_xor(a2, 32);
  a3 += __shfl_xor(a3, 32);
  if (half == 0) {
    int c = l * 4;
    float4 rt = *(const float4*)(rootsrc + (size_t)d * CC + c);
    float4 bs = *(const float4*)(bias + c);
    float v0 = fmaxf(a0 + rt.x + bs.x, 0.f);
    float v1 = fmaxf(a1 + rt.y + bs.y, 0.f);
    float v2 = fmaxf(a2 + rt.z + bs.z, 0.f);
    float v3 = fmaxf(a3 + rt.w + bs.w, 0.f);
    *(float4*)(h3 + (size_t)d * H3C + c) = make_float4(v0, v1, v2, v3);
    ushort_t pk[4] = {f2bf(v0), f2bf(v1), f2bf(v2), f2bf(v3)};
    *(uint2*)(xb + (size_t)d * 256 + c) = *(const uint2*)pk;
  }
}

// Basis-slot aggregation: z[d][b*K + c] = sum_edges (comp[r][b]/cnt_rd) * x[src][c]
// K=128: half-wave edge split, 4 ch/lane-half. K=256: full wave, 4 ch/lane.
template <int K>
__global__ __launch_bounds__(256) void aggz_k(const int* __restrict__ off,
                                              const uint2* __restrict__ payload,
                                              const float* __restrict__ comp,
                                              const ushort_t* __restrict__ xsrc,
                                              ushort_t* __restrict__ z) {
  __shared__ float comps[RR * BB];
  if (threadIdx.x < RR * BB) comps[threadIdx.x] = comp[threadIdx.x];
  __syncthreads();
  int wave = threadIdx.x >> 6, lane = threadIdx.x & 63;
  int d = blockIdx.x * 4 + wave;
  if (d >= NN) return;
  int beg = off[d], end = off[d + 1];
  float a[BB][4] = {};
  if (K == 128) {
    int half = lane >> 5, l = lane & 31;
    int c0 = l * 4;
    for (int i = beg + half; i < end; i += 2) {
      uint2 p = payload[i];
      int r = (int)(p.x >> 20);
      uint2 v = *(const uint2*)(xsrc + (size_t)(p.x & 0xFFFFFu) * 256 + c0);
      float w = __uint_as_float(p.y);
      float x0 = bf2f((ushort_t)(v.x & 0xFFFFu)), x1 = bf2f((ushort_t)(v.x >> 16));
      float x2 = bf2f((ushort_t)(v.y & 0xFFFFu)), x3 = bf2f((ushort_t)(v.y >> 16));
#pragma unroll
      for (int b = 0; b < BB; ++b) {
        float wb = w * comps[r * BB + b];
        a[b][0] += wb * x0;
        a[b][1] += wb * x1;
        a[b][2] += wb * x2;
        a[b][3] += wb * x3;
      }
    }
#pragma unroll
    for (int b = 0; b < BB; ++b)
#pragma unroll
      for (int j = 0; j < 4; ++j) a[b][j] += __shfl_xor(a[b][j], 32);
    if (half == 0) {
#pragma unroll
      for (int b = 0; b < BB; ++b) {
        ushort_t pk[4] = {f2bf(a[b][0]), f2bf(a[b][1]), f2bf(a[b][2]), f2bf(a[b][3])};
        *(uint2*)(z + (size_t)d * (4 * 128) + b * 128 + c0) = *(const uint2*)pk;
      }
    }
  } else {  // K == 256
    int c0 = lane * 4;
    for (int i = beg; i < end; ++i) {
      uint2 p = payload[i];
      int r = (int)(p.x >> 20);
      uint2 v = *(const uint2*)(xsrc + (size_t)(p.x & 0xFFFFFu) * 256 + c0);
      float w = __uint_as_float(p.y);
      float x0 = bf2f((ushort_t)(v.x & 0xFFFFu)), x1 = bf2f((ushort_t)(v.x >> 16));
      float x2 = bf2f((ushort_t)(v.y & 0xFFFFu)), x3 = bf2f((ushort_t)(v.y >> 16));
#pragma unroll
      for (int b = 0; b < BB; ++b) {
        float wb = w * comps[r * BB + b];
        a[b][0] += wb * x0;
        a[b][1] += wb * x1;
        a[b][2] += wb * x2;
        a[b][3] += wb * x3;
      }
    }
#pragma unroll
    for (int b = 0; b < BB; ++b) {
      ushort_t pk[4] = {f2bf(a[b][0]), f2bf(a[b][1]), f2bf(a[b][2]), f2bf(a[b][3])};
      *(uint2*)(z + (size_t)d * (4 * 256) + b * 256 + c0) = *(const uint2*)pk;
    }
  }
}

// Fragment-major stacked weights over KTOT = 5*K_IN rows (slots 0..3 = basis, 4 = root):
// Wt[((kk*8 + cb)*64 + lane)*8 + j] = W[kk*32 + (lane>>4)*8 + j][cb*16 + (lane&15)]
__global__ void makew3_k(const float* __restrict__ basis, const float* __restrict__ root,
                         ushort_t* __restrict__ Wt, int K_IN) {
  int f = blockIdx.x * 256 + threadIdx.x;
  int tot = 5 * K_IN * 16;  // fragments
  if (f >= tot) return;
  int kk = f >> 9;
  int rem = f & 511;
  int cb = rem >> 6, l = rem & 63;
  int fr = l & 15, fq = l >> 4;
  int c = cb * 16 + fr;
  int k0 = kk * 32 + fq * 8;
  ushort_t o[8];
#pragma unroll
  for (int j = 0; j < 8; ++j) {
    int k = k0 + j;
    int slot = k / K_IN, krem = k - slot * K_IN;
    float v = (slot < 4) ? basis[((size_t)slot * K_IN + krem) * CC + c]
                         : root[(size_t)krem * CC + c];
    o[j] = f2bf(v);
  }
  *(u16x8*)(Wt + (size_t)f * 8) = *(const u16x8*)o;
}

// Dense GEMM [N, 5K] @ [5K, 128]: A cols 0..4K-1 from z, 4K..5K-1 from xb.
// Block = 64 rows x 128 cols, 4 waves (2x2), wave tile 32x64, BK=64.
// Epilogue: relu(acc+bias) -> h3 column block (+ optional bf16 xb copy).
template <int K_IN, bool WXB>
__global__ __launch_bounds__(256) void gemm5_k(const ushort_t* __restrict__ z,
                                               const ushort_t* __restrict__ xb,
                                               const ushort_t* __restrict__ Wt,
                                               const float* __restrict__ bias,
                                               float* __restrict__ h3, int hoff,
                                               ushort_t* __restrict__ xbw, int xoff) {
  constexpr int ZK = 4 * K_IN;
  constexpr int NSTEPS = (5 * K_IN) / 64;
  constexpr int XST = 72;  // LDS A row stride (u16)
  __shared__ ushort_t xs[64 * XST];
  __shared__ ushort_t wls[64 * 128];
  int t = threadIdx.x;
  int wave = t >> 6, lane = t & 63;
  int wr = wave >> 1, wc = wave & 1;
  int fr = lane & 15, fq = lane >> 4;
  int row0 = blockIdx.x * 64;

  u16x8 areg0, areg1, breg[4];
  auto stage = [&](int step) {
    int k0 = step * 64;
    const ushort_t* base;
    int stride;
    if (k0 < ZK) {
      base = z + k0;
      stride = ZK;
    } else {
      base = xb + (k0 - ZK);
      stride = 256;
    }
    {
      int row = t >> 3, seg = t & 7;
      int gr = row0 + row;
      if (gr >= NN) gr = NN - 1;
      areg0 = *(const u16x8*)(base + (size_t)gr * stride + seg * 8);
      row = (t + 256) >> 3;
      gr = row0 + row;
      if (gr >= NN) gr = NN - 1;
      areg1 = *(const u16x8*)(base + (size_t)gr * stride + seg * 8);
    }
    const ushort_t* bsrc = Wt + (size_t)step * 8192;
#pragma unroll
    for (int q = 0; q < 4; ++q)
      breg[q] = *(const u16x8*)(bsrc + (size_t)(t + q * 256) * 8);
  };

  f32x4 acc[2][4];
#pragma unroll
  for (int rf = 0; rf < 2; ++rf)
#pragma unroll
    for (int cb = 0; cb < 4; ++cb) acc[rf][cb] = (f32x4){0.f, 0.f, 0.f, 0.f};

  stage(0);
  for (int step = 0; step < NSTEPS; ++step) {
    __syncthreads();
    {
      int row = t >> 3, seg = t & 7;
      *(u16x8*)(xs + row * XST + seg * 8) = areg0;
      row = (t + 256) >> 3;
      *(u16x8*)(xs + row * XST + seg * 8) = areg1;
    }
#pragma unroll
    for (int q = 0; q < 4; ++q)
      *(u16x8*)(wls + (size_t)(t + q * 256) * 8) = breg[q];
    __syncthreads();
    if (step + 1 < NSTEPS) stage(step + 1);
#pragma unroll
    for (int kk = 0; kk < 2; ++kk) {
      bf16x8 a0 = *(const bf16x8*)(xs + (wr * 32 + fr) * XST + kk * 32 + fq * 8);
      bf16x8 a1 = *(const bf16x8*)(xs + (wr * 32 + 16 + fr) * XST + kk * 32 + fq * 8);
#pragma unroll
      for (int cb = 0; cb < 4; ++cb) {
        bf16x8 b = *(const bf16x8*)(wls + ((kk * 8 + wc * 4 + cb) * 64 + lane) * 8);
        acc[0][cb] = __builtin_amdgcn_mfma_f32_16x16x32_bf16(a0, b, acc[0][cb], 0, 0, 0);
        acc[1][cb] = __builtin_amdgcn_mfma_f32_16x16x32_bf16(a1, b, acc[1][cb], 0, 0, 0);
      }
    }
  }

#pragma unroll
  for (int rf = 0; rf < 2; ++rf)
#pragma unroll
    for (int cb = 0; cb < 4; ++cb) {
      int c = wc * 64 + cb * 16 + fr;
      float bs = bias[c];
#pragma unroll
      for (int j = 0; j < 4; ++j) {
        int n = row0 + wr * 32 + rf * 16 + fq * 4 + j;
        if (n < NN) {
          float v = fmaxf(acc[rf][cb][j] + bs, 0.f);
          h3[(size_t)n * H3C + hoff + c] = v;
          if (WXB) xbw[(size_t)n * 256 + xoff + c] = f2bf(v);
        }
      }
    }
}

// In-place log_softmax over 384 channels; one 64-lane wave per node.
__global__ void logsoftmax_k(float* __restrict__ h) {
  int n = blockIdx.x;
  int l = threadIdx.x;
  float* row = h + (size_t)n * H3C;
  float vals[6];
  float m = -1e30f;
#pragma unroll
  for (int j = 0; j < 6; ++j) {
    vals[j] = row[l + 64 * j];
    m = fmaxf(m, vals[j]);
  }
#pragma unroll
  for (int off = 32; off > 0; off >>= 1) m = fmaxf(m, __shfl_xor(m, off));
  float s = 0.f;
#pragma unroll
  for (int j = 0; j < 6; ++j) s += expf(vals[j] - m);
#pragma unroll
  for (int off = 32; off > 0; off >>= 1) s += __shfl_xor(s, off);
  float ls = logf(s);
#pragma unroll
  for (int j = 0; j < 6; ++j) row[l + 64 * j] = vals[j] - m - ls;
}

extern "C" void kernel_launch(void* const* d_in, const int* in_sizes, int n_in,
                              void* d_out, int out_size, void* d_ws, size_t ws_size,
                              hipStream_t stream) {
  const int* ei = (const int*)d_in[0];
  const int* et = (const int*)d_in[1];
  const float* basis1 = (const float*)d_in[2];
  const float* comp1 = (const float*)d_in[3];
  const float* root1 = (const float*)d_in[4];
  const float* bias1 = (const float*)d_in[5];
  const float* basis_b0 = (const float*)d_in[6];
  const float* comp_b0 = (const float*)d_in[7];
  const float* root_b0 = (const float*)d_in[8];
  const float* bias_b0 = (const float*)d_in[9];
  const float* basis_b1 = (const float*)d_in[10];
  const float* comp_b1 = (const float*)d_in[11];
  const float* root_b1 = (const float*)d_in[12];
  const float* bias_b1 = (const float*)d_in[13];
  float* out = (float*)d_out;  // [N][384] h3 storage
  char* ws = (char*)d_ws;

  uint2* payload = (uint2*)ws;                           // E * 8B = 4 MB
  ushort_t* hrz = (ushort_t*)(payload + EE);             // max(hr1, z) = 8*N*C u16 = 102.4 MB
  ushort_t* xb = hrz + (size_t)RR * NN * CC;             // N*256 u16 = 25.6 MB
  ushort_t* wt = xb + (size_t)NN * 256;                  // 1280*128 u16 = 0.33 MB
  int* cnt_rd = (int*)(wt + (size_t)1280 * 128);         // R*N int
  int* cur = cnt_rd + (size_t)RR * NN;                   // N int
  int* off = cur + NN;                                   // N+1 int
  int* bsum = off + NN + 1;
  int* bbase = bsum + 256;
  size_t need = (size_t)((char*)(bbase + 256) - ws);
  if (ws_size < need) return;

  // --- CSR build ---
  zero_int_k<<<(RR * NN + NN + 255) / 256, 256, 0, stream>>>(cnt_rd, RR * NN + NN);
  count_k<<<(EE + 255) / 256, 256, 0, stream>>>(ei, et, cnt_rd);
  scanA_k<<<NB, 256, 0, stream>>>(cnt_rd, off, bsum);
  scanB_k<<<1, 256, 0, stream>>>(bsum, bbase);
  scanC_k<<<NB, 256, 0, stream>>>(off, bbase);
  fill_k<<<(EE + 255) / 256, 256, 0, stream>>>(ei, et, cnt_rd, off, cur, payload);

  const int NC_BLKS = (NN * CC + 255) / 256;
  const int AG_BLKS = (NN + 3) / 4;
  const int GE_BLKS = (NN + 63) / 64;  // 782

  // --- layer 1 (hr1 in hrz) ---
  makehr1_k<<<NC_BLKS, 256, 0, stream>>>(basis1, comp1, hrz);
  aggr_k<<<AG_BLKS, 256, 0, stream>>>(off, payload, hrz, root1, bias1, out, xb);

  // --- layer 2 (K=128): z aliases hrz (hr1 dead after aggr_k) ---
  makew3_k<<<(5 * 128 * 16 + 255) / 256, 256, 0, stream>>>(basis_b0, root_b0, wt, 128);
  aggz_k<128><<<AG_BLKS, 256, 0, stream>>>(off, payload, comp_b0, xb, hrz);
  gemm5_k<128, true><<<GE_BLKS, 256, 0, stream>>>(hrz, xb, wt, bias_b0, out, CC, xb, CC);

  // --- layer 3 (K=256) ---
  makew3_k<<<(5 * 256 * 16 + 255) / 256, 256, 0, stream>>>(basis_b1, root_b1, wt, 256);
  aggz_k<256><<<AG_BLKS, 256, 0, stream>>>(off, payload, comp_b1, xb, hrz);
  gemm5_k<256, false><<<GE_BLKS, 256, 0, stream>>>(hrz, xb, wt, bias_b1, out, 2 * CC, nullptr, 0);

  // --- log_softmax in place ---
  logsoftmax_k<<<NN, 64, 0, stream>>>(out);
}

// Round 8
// 304.390 us; speedup vs baseline: 1.3237x; 1.1558x over previous
//
#include <hip/hip_runtime.h>
#include <cstdint>
#include <cstddef>

#define NN 50000
#define EE 500000
#define RR 8
#define CC 128
#define BB 4
#define H3C 384
#define NB 196  // ceil(NN/256)
#define YS 64.0f
#define YSI (1.0f / 64.0f)

typedef unsigned short ushort_t;
typedef __bf16 bf16x8 __attribute__((ext_vector_type(8)));
typedef float f32x4 __attribute__((ext_vector_type(4)));
typedef float f32x2 __attribute__((ext_vector_type(2)));
typedef unsigned short u16x8 __attribute__((ext_vector_type(8)));

static __device__ __forceinline__ ushort_t f2bf(float f) {
  unsigned u = __float_as_uint(f);
  unsigned r = (u + 0x7fffu + ((u >> 16) & 1u)) >> 16;
  return (ushort_t)r;
}
static __device__ __forceinline__ float bf2f(ushort_t u) {
  return __uint_as_float(((unsigned)u) << 16);
}

__global__ void zero_int_k(int* p, int n) {
  int i = blockIdx.x * 256 + threadIdx.x;
  if (i < n) p[i] = 0;
}

__global__ void count_k(const int* __restrict__ ei, const int* __restrict__ et, int* cnt) {
  int e = blockIdx.x * 256 + threadIdx.x;
  if (e >= EE) return;
  int d = ei[EE + e];
  int r = et[e];
  atomicAdd(&cnt[r * NN + d], 1);
}

__global__ __launch_bounds__(256) void scanA_k(const int* __restrict__ cnt_rd, int* off, int* bsum) {
  __shared__ int s[256];
  int t = threadIdx.x;
  int i = blockIdx.x * 256 + t;
  int v = 0;
  if (i < NN) {
#pragma unroll
    for (int r = 0; r < RR; ++r) v += cnt_rd[r * NN + i];
  }
  s[t] = v;
  __syncthreads();
  for (int d = 1; d < 256; d <<= 1) {
    int x = (t >= d) ? s[t - d] : 0;
    __syncthreads();
    s[t] += x;
    __syncthreads();
  }
  if (i < NN) off[i] = s[t] - v;
  if (t == 255) bsum[blockIdx.x] = s[255];
}

__global__ __launch_bounds__(256) void scanB_k(const int* __restrict__ bsum, int* bbase) {
  __shared__ int s[256];
  int t = threadIdx.x;
  int v = (t < NB) ? bsum[t] : 0;
  s[t] = v;
  __syncthreads();
  for (int d = 1; d < 256; d <<= 1) {
    int x = (t >= d) ? s[t - d] : 0;
    __syncthreads();
    s[t] += x;
    __syncthreads();
  }
  if (t < NB) bbase[t] = s[t] - v;
}

__global__ void scanC_k(int* off, const int* __restrict__ bbase) {
  int i = blockIdx.x * 256 + threadIdx.x;
  if (i < NN) off[i] += bbase[i >> 8];
  if (i == 0) off[NN] = EE;
}

// Scatter edges into CSR slots; payload = {src | (r<<20), bits(1/max(cnt_rd,1))}.
__global__ void fill_k(const int* __restrict__ ei, const int* __restrict__ et,
                       const int* __restrict__ cnt_rd, const int* __restrict__ off,
                       int* cur, uint2* __restrict__ payload) {
  int e = blockIdx.x * 256 + threadIdx.x;
  if (e >= EE) return;
  int s = ei[e], d = ei[EE + e], r = et[e];
  int pos = off[d] + atomicAdd(&cur[d], 1);
  float w = 1.0f / (float)max(cnt_rd[r * NN + d], 1);
  payload[pos] = make_uint2((unsigned)s | ((unsigned)r << 20), __float_as_uint(w));
}

// Layer-1 "y": yq[n][b*128+c] = fp8(YS * basis1[b][n][c])
__global__ void makebasisq_k(const float* __restrict__ basis1, unsigned char* __restrict__ yq) {
  int u = blockIdx.x * 256 + threadIdx.x;
  if (u >= NN * 128) return;
  int n = u >> 7, q = u & 127;
  int b = q >> 5, c0 = (q & 31) * 4;
  float4 v = *(const float4*)(basis1 + ((size_t)b * NN + n) * CC + c0);
  int pk = __builtin_amdgcn_cvt_pk_fp8_f32(v.x * YS, v.y * YS, 0, false);
  pk = __builtin_amdgcn_cvt_pk_fp8_f32(v.z * YS, v.w * YS, pk, true);
  *(unsigned*)(yq + (size_t)n * 512 + b * 128 + c0) = (unsigned)pk;
}

// y-form aggregation: x_out[d][c] = relu( sum_e sum_b (w*comp[r][b]/YS)*y_b[src][c]
//                                          + rootsrc[d][c] + bias[c] ) -> bf16 xb.
// One wave per node; half-wave edge split; lane-half handles 4 channels.
__global__ __launch_bounds__(256) void aggry_k(const int* __restrict__ off,
                                               const uint2* __restrict__ payload,
                                               const unsigned char* __restrict__ yq,
                                               const float* __restrict__ comp,
                                               const float* __restrict__ rootsrc,
                                               const float* __restrict__ bias,
                                               ushort_t* __restrict__ xbw, int xoff) {
  __shared__ float comps[RR * BB];
  if (threadIdx.x < RR * BB) comps[threadIdx.x] = comp[threadIdx.x] * YSI;
  __syncthreads();
  int wave = threadIdx.x >> 6, lane = threadIdx.x & 63;
  int d = blockIdx.x * 4 + wave;
  if (d >= NN) return;
  int beg = off[d], end = off[d + 1];
  int half = lane >> 5, l = lane & 31;
  float a0 = 0.f, a1 = 0.f, a2 = 0.f, a3 = 0.f;
  for (int i = beg + half; i < end; i += 2) {
    uint2 p = payload[i];
    const unsigned char* row = yq + (size_t)(p.x & 0xFFFFFu) * 512 + l * 4;
    unsigned u0 = *(const unsigned*)row;
    unsigned u1 = *(const unsigned*)(row + 128);
    unsigned u2 = *(const unsigned*)(row + 256);
    unsigned u3 = *(const unsigned*)(row + 384);
    float w = __uint_as_float(p.y);
    int r4 = (int)(p.x >> 20) * BB;
    float w0 = w * comps[r4 + 0], w1 = w * comps[r4 + 1];
    float w2 = w * comps[r4 + 2], w3 = w * comps[r4 + 3];
    f32x2 lo = __builtin_amdgcn_cvt_pk_f32_fp8(u0, false);
    f32x2 hi = __builtin_amdgcn_cvt_pk_f32_fp8(u0, true);
    a0 += w0 * lo.x; a1 += w0 * lo.y; a2 += w0 * hi.x; a3 += w0 * hi.y;
    lo = __builtin_amdgcn_cvt_pk_f32_fp8(u1, false);
    hi = __builtin_amdgcn_cvt_pk_f32_fp8(u1, true);
    a0 += w1 * lo.x; a1 += w1 * lo.y; a2 += w1 * hi.x; a3 += w1 * hi.y;
    lo = __builtin_amdgcn_cvt_pk_f32_fp8(u2, false);
    hi = __builtin_amdgcn_cvt_pk_f32_fp8(u2, true);
    a0 += w2 * lo.x; a1 += w2 * lo.y; a2 += w2 * hi.x; a3 += w2 * hi.y;
    lo = __builtin_amdgcn_cvt_pk_f32_fp8(u3, false);
    hi = __builtin_amdgcn_cvt_pk_f32_fp8(u3, true);
    a0 += w3 * lo.x; a1 += w3 * lo.y; a2 += w3 * hi.x; a3 += w3 * hi.y;
  }
  a0 += __shfl_xor(a0, 32);
  a1 += __shfl_xor(a1, 32);
  a2 += __shfl_xor(a2, 32);
  a3 += __shfl_xor(a3, 32);
  if (half == 0) {
    int c = l * 4;
    float4 rt = *(const float4*)(rootsrc + (size_t)d * CC + c);
    float4 bs = *(const float4*)(bias + c);
    float v0 = fmaxf(a0 + rt.x + bs.x, 0.f);
    float v1 = fmaxf(a1 + rt.y + bs.y, 0.f);
    float v2 = fmaxf(a2 + rt.z + bs.z, 0.f);
    float v3 = fmaxf(a3 + rt.w + bs.w, 0.f);
    ushort_t pk[4] = {f2bf(v0), f2bf(v1), f2bf(v2), f2bf(v3)};
    *(uint2*)(xbw + (size_t)d * 256 + xoff + c) = *(const uint2*)pk;
  }
}

// Layer-3 aggregation + fused relu + log_softmax over 384 cols; writes d_out.
__global__ __launch_bounds__(256) void aggrsm_k(const int* __restrict__ off,
                                                const uint2* __restrict__ payload,
                                                const unsigned char* __restrict__ yq,
                                                const float* __restrict__ comp,
                                                const float* __restrict__ rootsrc,
                                                const float* __restrict__ bias,
                                                const ushort_t* __restrict__ xb,
                                                float* __restrict__ out) {
  __shared__ float comps[RR * BB];
  if (threadIdx.x < RR * BB) comps[threadIdx.x] = comp[threadIdx.x] * YSI;
  __syncthreads();
  int wave = threadIdx.x >> 6, lane = threadIdx.x & 63;
  int d = blockIdx.x * 4 + wave;
  if (d >= NN) return;
  int beg = off[d], end = off[d + 1];
  int half = lane >> 5, l = lane & 31;
  float a0 = 0.f, a1 = 0.f, a2 = 0.f, a3 = 0.f;
  for (int i = beg + half; i < end; i += 2) {
    uint2 p = payload[i];
    const unsigned char* row = yq + (size_t)(p.x & 0xFFFFFu) * 512 + l * 4;
    unsigned u0 = *(const unsigned*)row;
    unsigned u1 = *(const unsigned*)(row + 128);
    unsigned u2 = *(const unsigned*)(row + 256);
    unsigned u3 = *(const unsigned*)(row + 384);
    float w = __uint_as_float(p.y);
    int r4 = (int)(p.x >> 20) * BB;
    float w0 = w * comps[r4 + 0], w1 = w * comps[r4 + 1];
    float w2 = w * comps[r4 + 2], w3 = w * comps[r4 + 3];
    f32x2 lo = __builtin_amdgcn_cvt_pk_f32_fp8(u0, false);
    f32x2 hi = __builtin_amdgcn_cvt_pk_f32_fp8(u0, true);
    a0 += w0 * lo.x; a1 += w0 * lo.y; a2 += w0 * hi.x; a3 += w0 * hi.y;
    lo = __builtin_amdgcn_cvt_pk_f32_fp8(u1, false);
    hi = __builtin_amdgcn_cvt_pk_f32_fp8(u1, true);
    a0 += w1 * lo.x; a1 += w1 * lo.y; a2 += w1 * hi.x; a3 += w1 * hi.y;
    lo = __builtin_amdgcn_cvt_pk_f32_fp8(u2, false);
    hi = __builtin_amdgcn_cvt_pk_f32_fp8(u2, true);
    a0 += w2 * lo.x; a1 += w2 * lo.y; a2 += w2 * hi.x; a3 += w2 * hi.y;
    lo = __builtin_amdgcn_cvt_pk_f32_fp8(u3, false);
    hi = __builtin_amdgcn_cvt_pk_f32_fp8(u3, true);
    a0 += w3 * lo.x; a1 += w3 * lo.y; a2 += w3 * hi.x; a3 += w3 * hi.y;
  }
  a0 += __shfl_xor(a0, 32);
  a1 += __shfl_xor(a1, 32);
  a2 += __shfl_xor(a2, 32);
  a3 += __shfl_xor(a3, 32);
  // all lanes: channels c0..c0+3 where c0 = 4*(lane&31)
  int c0 = (lane & 31) * 4;
  float4 rt = *(const float4*)(rootsrc + (size_t)d * CC + c0);
  float4 bs = *(const float4*)(bias + c0);
  float h0 = fmaxf(a0 + rt.x + bs.x, 0.f);
  float h1 = fmaxf(a1 + rt.y + bs.y, 0.f);
  float h2 = fmaxf(a2 + rt.z + bs.z, 0.f);
  float h3v = fmaxf(a3 + rt.w + bs.w, 0.f);
  float vals[6];
#pragma unroll
  for (int jj = 0; jj < 4; ++jj)
    vals[jj] = bf2f(xb[(size_t)d * 256 + jj * 64 + lane]);
  int s4 = lane >> 2, e = lane & 3;
  {
    float b0 = __shfl(h0, s4), b1 = __shfl(h1, s4), b2 = __shfl(h2, s4), b3 = __shfl(h3v, s4);
    float x01 = (e & 1) ? b1 : b0, x23 = (e & 1) ? b3 : b2;
    vals[4] = (e & 2) ? x23 : x01;
  }
  {
    int s5 = 16 + s4;
    float b0 = __shfl(h0, s5), b1 = __shfl(h1, s5), b2 = __shfl(h2, s5), b3 = __shfl(h3v, s5);
    float x01 = (e & 1) ? b1 : b0, x23 = (e & 1) ? b3 : b2;
    vals[5] = (e & 2) ? x23 : x01;
  }
  float m = vals[0];
#pragma unroll
  for (int jj = 1; jj < 6; ++jj) m = fmaxf(m, vals[jj]);
#pragma unroll
  for (int o = 32; o > 0; o >>= 1) m = fmaxf(m, __shfl_xor(m, o));
  float ssum = 0.f;
#pragma unroll
  for (int jj = 0; jj < 6; ++jj) ssum += expf(vals[jj] - m);
#pragma unroll
  for (int o = 32; o > 0; o >>= 1) ssum += __shfl_xor(ssum, o);
  float ls = logf(ssum);
#pragma unroll
  for (int jj = 0; jj < 6; ++jj)
    out[(size_t)d * H3C + jj * 64 + lane] = vals[jj] - m - ls;
}

// Fragment-major weights for 5 slots (0..3 = basis V_b [K_IN,128], 4 = root):
// Wt[(((s*(K/32)+kk)*8 + cb)*64 + lane)*8 + j] = W_s[kk*32+(lane>>4)*8+j][cb*16+(lane&15)]
template <int K_IN>
__global__ void makew5_k(const float* __restrict__ basis, const float* __restrict__ root,
                         ushort_t* __restrict__ Wt) {
  int f = blockIdx.x * 256 + threadIdx.x;
  constexpr int KD = K_IN / 32;
  int tot = 5 * KD * 8 * 64;
  if (f >= tot) return;
  int l = f & 63;
  int fi = f >> 6;
  int cb = fi & 7;
  int rem = fi >> 3;
  int kk = rem & (KD - 1);
  int s = rem / KD;
  int fr = l & 15, fq = l >> 4;
  int c = cb * 16 + fr;
  int k0 = kk * 32 + fq * 8;
  ushort_t o[8];
#pragma unroll
  for (int j = 0; j < 8; ++j) {
    int k = k0 + j;
    float v = (s < 4) ? basis[((size_t)s * K_IN + k) * CC + c]
                      : root[(size_t)k * CC + c];
    o[j] = f2bf(v);
  }
  *(u16x8*)(Wt + (size_t)f * 8) = *(const u16x8*)o;
}

// y GEMM: per slot s (blockIdx.y): y_s = x @ W_s.  s<4 -> fp8*YS into yq
// (via LDS repack); s==4 -> f32 yroot.  Block 64r x 128c, 4 waves 2x2, BK=64.
template <int K_IN>
__global__ __launch_bounds__(256) void gemmy_k(const ushort_t* __restrict__ xb,
                                               const ushort_t* __restrict__ Wt,
                                               unsigned char* __restrict__ yq,
                                               float* __restrict__ yroot) {
  constexpr int NSTEPS = K_IN / 64;
  constexpr int XST = 72;
  __shared__ char smem[64 * 132 * 4];  // 33792 B; phases: (xs|wls) then repack
  ushort_t* xs = (ushort_t*)smem;                     // 64*72*2 = 9216 B
  ushort_t* wls = (ushort_t*)(smem + 64 * XST * 2);   // 16384 B
  int t = threadIdx.x;
  int wave = t >> 6, lane = t & 63;
  int wr = wave >> 1, wc = wave & 1;
  int fr = lane & 15, fq = lane >> 4;
  int row0 = blockIdx.x * 64;
  int s = blockIdx.y;
  const ushort_t* wslot = Wt + (size_t)s * (K_IN * 128);

  u16x8 areg0, areg1, breg[4];
  auto stage = [&](int step) {
    int seg = t & 7;
    int row = t >> 3;
    int gr = row0 + row;
    if (gr >= NN) gr = NN - 1;
    areg0 = *(const u16x8*)(xb + (size_t)gr * 256 + step * 64 + seg * 8);
    row = (t + 256) >> 3;
    gr = row0 + row;
    if (gr >= NN) gr = NN - 1;
    areg1 = *(const u16x8*)(xb + (size_t)gr * 256 + step * 64 + seg * 8);
    const ushort_t* bsrc = wslot + (size_t)step * 8192;
#pragma unroll
    for (int q = 0; q < 4; ++q)
      breg[q] = *(const u16x8*)(bsrc + (size_t)(t + q * 256) * 8);
  };

  f32x4 acc[2][4];
#pragma unroll
  for (int rf = 0; rf < 2; ++rf)
#pragma unroll
    for (int cb = 0; cb < 4; ++cb) acc[rf][cb] = (f32x4){0.f, 0.f, 0.f, 0.f};

  stage(0);
  for (int step = 0; step < NSTEPS; ++step) {
    __syncthreads();
    {
      int seg = t & 7;
      *(u16x8*)(xs + (t >> 3) * XST + seg * 8) = areg0;
      *(u16x8*)(xs + ((t + 256) >> 3) * XST + seg * 8) = areg1;
    }
#pragma unroll
    for (int q = 0; q < 4; ++q)
      *(u16x8*)(wls + (size_t)(t + q * 256) * 8) = breg[q];
    __syncthreads();
    if (step + 1 < NSTEPS) stage(step + 1);
#pragma unroll
    for (int kk = 0; kk < 2; ++kk) {
      bf16x8 a0 = *(const bf16x8*)(xs + (wr * 32 + fr) * XST + kk * 32 + fq * 8);
      bf16x8 a1 = *(const bf16x8*)(xs + (wr * 32 + 16 + fr) * XST + kk * 32 + fq * 8);
#pragma unroll
      for (int cb = 0; cb < 4; ++cb) {
        bf16x8 b = *(const bf16x8*)(wls + ((kk * 8 + wc * 4 + cb) * 64 + lane) * 8);
        acc[0][cb] = __builtin_amdgcn_mfma_f32_16x16x32_bf16(a0, b, acc[0][cb], 0, 0, 0);
        acc[1][cb] = __builtin_amdgcn_mfma_f32_16x16x32_bf16(a1, b, acc[1][cb], 0, 0, 0);
      }
    }
  }

  if (s == 4) {
#pragma unroll
    for (int rf = 0; rf < 2; ++rf)
#pragma unroll
      for (int cb = 0; cb < 4; ++cb) {
        int c = wc * 64 + cb * 16 + fr;
#pragma unroll
        for (int j = 0; j < 4; ++j) {
          int n = row0 + wr * 32 + rf * 16 + fq * 4 + j;
          if (n < NN) yroot[(size_t)n * CC + c] = acc[rf][cb][j];
        }
      }
  } else {
    __syncthreads();
    float* rp = (float*)smem;  // [64][132]
#pragma unroll
    for (int rf = 0; rf < 2; ++rf)
#pragma unroll
      for (int cb = 0; cb < 4; ++cb)
#pragma unroll
        for (int j = 0; j < 4; ++j)
          rp[(wr * 32 + rf * 16 + fq * 4 + j) * 132 + wc * 64 + cb * 16 + fr] = acc[rf][cb][j];
    __syncthreads();
    int row = t & 63, c0 = (t >> 6) * 32;
    int gr = row0 + row;
    if (gr < NN) {
      const float* src = rp + row * 132 + c0;
      unsigned ub[8];
#pragma unroll
      for (int q = 0; q < 8; ++q) {
        float4 v = *(const float4*)(src + q * 4);
        int pk = __builtin_amdgcn_cvt_pk_fp8_f32(v.x * YS, v.y * YS, 0, false);
        pk = __builtin_amdgcn_cvt_pk_fp8_f32(v.z * YS, v.w * YS, pk, true);
        ub[q] = (unsigned)pk;
      }
      unsigned char* dst = yq + (size_t)gr * 512 + s * 128 + c0;
      *(uint4*)dst = make_uint4(ub[0], ub[1], ub[2], ub[3]);
      *(uint4*)(dst + 16) = make_uint4(ub[4], ub[5], ub[6], ub[7]);
    }
  }
}

extern "C" void kernel_launch(void* const* d_in, const int* in_sizes, int n_in,
                              void* d_out, int out_size, void* d_ws, size_t ws_size,
                              hipStream_t stream) {
  const int* ei = (const int*)d_in[0];
  const int* et = (const int*)d_in[1];
  const float* basis1 = (const float*)d_in[2];
  const float* comp1 = (const float*)d_in[3];
  const float* root1 = (const float*)d_in[4];
  const float* bias1 = (const float*)d_in[5];
  const float* basis_b0 = (const float*)d_in[6];
  const float* comp_b0 = (const float*)d_in[7];
  const float* root_b0 = (const float*)d_in[8];
  const float* bias_b0 = (const float*)d_in[9];
  const float* basis_b1 = (const float*)d_in[10];
  const float* comp_b1 = (const float*)d_in[11];
  const float* root_b1 = (const float*)d_in[12];
  const float* bias_b1 = (const float*)d_in[13];
  float* out = (float*)d_out;  // [N][384]
  char* ws = (char*)d_ws;

  uint2* payload = (uint2*)ws;                            // 4 MB
  float* yroot = (float*)(payload + EE);                  // N*128 f32 = 25.6 MB
  ushort_t* xb = (ushort_t*)(yroot + (size_t)NN * CC);    // N*256 bf16 = 25.6 MB
  ushort_t* wt = xb + (size_t)NN * 256;                   // 327680 u16 = 0.66 MB
  unsigned char* yq = (unsigned char*)(wt + 327680);      // N*512 fp8 = 25.6 MB
  int* cnt_rd = (int*)(yq + (size_t)NN * 512);            // R*N int
  int* cur = cnt_rd + (size_t)RR * NN;                    // N int
  int* off = cur + NN;                                    // N+1 int
  int* bsum = off + NN + 1;
  int* bbase = bsum + 256;
  size_t need = (size_t)((char*)(bbase + 256) - ws);
  if (ws_size < need) return;

  // --- CSR build ---
  zero_int_k<<<(RR * NN + NN + 255) / 256, 256, 0, stream>>>(cnt_rd, RR * NN + NN);
  count_k<<<(EE + 255) / 256, 256, 0, stream>>>(ei, et, cnt_rd);
  scanA_k<<<NB, 256, 0, stream>>>(cnt_rd, off, bsum);
  scanB_k<<<1, 256, 0, stream>>>(bsum, bbase);
  scanC_k<<<NB, 256, 0, stream>>>(off, bbase);
  fill_k<<<(EE + 255) / 256, 256, 0, stream>>>(ei, et, cnt_rd, off, cur, payload);

  const int AG_BLKS = (NN + 3) / 4;
  const int GE_BLKS = (NN + 63) / 64;  // 782
  dim3 gy(GE_BLKS, 5);

  // --- layer 1: y = quantized basis1 ---
  makebasisq_k<<<(NN * 128 + 255) / 256, 256, 0, stream>>>(basis1, yq);
  aggry_k<<<AG_BLKS, 256, 0, stream>>>(off, payload, yq, comp1, root1, bias1, xb, 0);

  // --- layer 2 (K=128) ---
  makew5_k<128><<<(5 * 4 * 8 * 64 + 255) / 256, 256, 0, stream>>>(basis_b0, root_b0, wt);
  gemmy_k<128><<<gy, 256, 0, stream>>>(xb, wt, yq, yroot);
  aggry_k<<<AG_BLKS, 256, 0, stream>>>(off, payload, yq, comp_b0, yroot, bias_b0, xb, CC);

  // --- layer 3 (K=256) + fused log_softmax ---
  makew5_k<256><<<(5 * 8 * 8 * 64 + 255) / 256, 256, 0, stream>>>(basis_b1, root_b1, wt);
  gemmy_k<256><<<gy, 256, 0, stream>>>(xb, wt, yq, yroot);
  aggrsm_k<<<AG_BLKS, 256, 0, stream>>>(off, payload, yq, comp_b1, yroot, bias_b1, xb, out);
}

// Round 9
// 283.141 us; speedup vs baseline: 1.4230x; 1.0750x over previous
//
#include <hip/hip_runtime.h>
#include <cstdint>
#include <cstddef>

#define NN 50000
#define EE 500000
#define RR 8
#define CC 128
#define BB 4
#define H3C 384
#define NB 196  // ceil(NN/256)
#define YS 64.0f
#define YSI (1.0f / 64.0f)

typedef unsigned short ushort_t;
typedef __bf16 bf16x8 __attribute__((ext_vector_type(8)));
typedef float f32x4 __attribute__((ext_vector_type(4)));
typedef float f32x2 __attribute__((ext_vector_type(2)));
typedef unsigned short u16x8 __attribute__((ext_vector_type(8)));

static __device__ __forceinline__ ushort_t f2bf(float f) {
  unsigned u = __float_as_uint(f);
  unsigned r = (u + 0x7fffu + ((u >> 16) & 1u)) >> 16;
  return (ushort_t)r;
}
static __device__ __forceinline__ float bf2f(ushort_t u) {
  return __uint_as_float(((unsigned)u) << 16);
}

__global__ void zero_int_k(int* p, int n) {
  int i = blockIdx.x * 256 + threadIdx.x;
  if (i < n) p[i] = 0;
}

__global__ void count_k(const int* __restrict__ ei, const int* __restrict__ et, int* cnt) {
  int e = blockIdx.x * 256 + threadIdx.x;
  if (e >= EE) return;
  int d = ei[EE + e];
  int r = et[e];
  atomicAdd(&cnt[r * NN + d], 1);
}

__global__ __launch_bounds__(256) void scanA_k(const int* __restrict__ cnt_rd, int* off, int* bsum) {
  __shared__ int s[256];
  int t = threadIdx.x;
  int i = blockIdx.x * 256 + t;
  int v = 0;
  if (i < NN) {
#pragma unroll
    for (int r = 0; r < RR; ++r) v += cnt_rd[r * NN + i];
  }
  s[t] = v;
  __syncthreads();
  for (int d = 1; d < 256; d <<= 1) {
    int x = (t >= d) ? s[t - d] : 0;
    __syncthreads();
    s[t] += x;
    __syncthreads();
  }
  if (i < NN) off[i] = s[t] - v;
  if (t == 255) bsum[blockIdx.x] = s[255];
}

__global__ __launch_bounds__(256) void scanB_k(const int* __restrict__ bsum, int* bbase) {
  __shared__ int s[256];
  int t = threadIdx.x;
  int v = (t < NB) ? bsum[t] : 0;
  s[t] = v;
  __syncthreads();
  for (int d = 1; d < 256; d <<= 1) {
    int x = (t >= d) ? s[t - d] : 0;
    __syncthreads();
    s[t] += x;
    __syncthreads();
  }
  if (t < NB) bbase[t] = s[t] - v;
}

__global__ void scanC_k(int* off, const int* __restrict__ bbase) {
  int i = blockIdx.x * 256 + threadIdx.x;
  if (i < NN) off[i] += bbase[i >> 8];
  if (i == 0) off[NN] = EE;
}

// Scatter edges into CSR slots; payload = {src | (r<<20), bits(1/max(cnt_rd,1))}.
__global__ void fill_k(const int* __restrict__ ei, const int* __restrict__ et,
                       const int* __restrict__ cnt_rd, const int* __restrict__ off,
                       int* cur, uint2* __restrict__ payload) {
  int e = blockIdx.x * 256 + threadIdx.x;
  if (e >= EE) return;
  int s = ei[e], d = ei[EE + e], r = et[e];
  int pos = off[d] + atomicAdd(&cur[d], 1);
  float w = 1.0f / (float)max(cnt_rd[r * NN + d], 1);
  payload[pos] = make_uint2((unsigned)s | ((unsigned)r << 20), __float_as_uint(w));
}

// Layer-1 message table: hrq[r][n][c] = fp8(YS * sum_b comp1[r][b]*basis1[b][n][c])
__global__ void makehr1q_k(const float* __restrict__ basis1, const float* __restrict__ comp1,
                           unsigned char* __restrict__ hrq) {
  __shared__ float comps[RR * BB];
  if (threadIdx.x < RR * BB) comps[threadIdx.x] = comp1[threadIdx.x] * YS;
  __syncthreads();
  int idx = blockIdx.x * 256 + threadIdx.x;  // n*32 + c4
  if (idx >= NN * 32) return;
  int n = idx >> 5, c0 = (idx & 31) * 4;
  float4 y[BB];
#pragma unroll
  for (int b = 0; b < BB; ++b)
    y[b] = *(const float4*)(basis1 + ((size_t)b * NN + n) * CC + c0);
#pragma unroll
  for (int r = 0; r < RR; ++r) {
    float k0 = comps[r * BB + 0], k1 = comps[r * BB + 1];
    float k2 = comps[r * BB + 2], k3 = comps[r * BB + 3];
    float v0 = k0 * y[0].x + k1 * y[1].x + k2 * y[2].x + k3 * y[3].x;
    float v1 = k0 * y[0].y + k1 * y[1].y + k2 * y[2].y + k3 * y[3].y;
    float v2 = k0 * y[0].z + k1 * y[1].z + k2 * y[2].z + k3 * y[3].z;
    float v3 = k0 * y[0].w + k1 * y[1].w + k2 * y[2].w + k3 * y[3].w;
    int pk = __builtin_amdgcn_cvt_pk_fp8_f32(v0, v1, 0, false);
    pk = __builtin_amdgcn_cvt_pk_fp8_f32(v2, v3, pk, true);
    *(unsigned*)(hrq + ((size_t)r * NN + n) * CC + c0) = (unsigned)pk;
  }
}

// Layers 2/3 message table: hrq[r][n][c] = fp8( sum_b comp[r][b] * yq_b[n][c] )
// (yq already carries the YS scale.)
__global__ void makehrq_k(const unsigned char* __restrict__ yq, const float* __restrict__ comp,
                          unsigned char* __restrict__ hrq) {
  __shared__ float comps[RR * BB];
  if (threadIdx.x < RR * BB) comps[threadIdx.x] = comp[threadIdx.x];
  __syncthreads();
  int idx = blockIdx.x * 256 + threadIdx.x;  // n*32 + c4
  if (idx >= NN * 32) return;
  int n = idx >> 5, c0 = (idx & 31) * 4;
  const unsigned char* yr = yq + (size_t)n * 512 + c0;
  float y[BB][4];
#pragma unroll
  for (int b = 0; b < BB; ++b) {
    unsigned u = *(const unsigned*)(yr + b * 128);
    f32x2 lo = __builtin_amdgcn_cvt_pk_f32_fp8(u, false);
    f32x2 hi = __builtin_amdgcn_cvt_pk_f32_fp8(u, true);
    y[b][0] = lo.x; y[b][1] = lo.y; y[b][2] = hi.x; y[b][3] = hi.y;
  }
#pragma unroll
  for (int r = 0; r < RR; ++r) {
    float k0 = comps[r * BB + 0], k1 = comps[r * BB + 1];
    float k2 = comps[r * BB + 2], k3 = comps[r * BB + 3];
    float v0 = k0 * y[0][0] + k1 * y[1][0] + k2 * y[2][0] + k3 * y[3][0];
    float v1 = k0 * y[0][1] + k1 * y[1][1] + k2 * y[2][1] + k3 * y[3][1];
    float v2 = k0 * y[0][2] + k1 * y[1][2] + k2 * y[2][2] + k3 * y[3][2];
    float v3 = k0 * y[0][3] + k1 * y[1][3] + k2 * y[2][3] + k3 * y[3][3];
    int pk = __builtin_amdgcn_cvt_pk_fp8_f32(v0, v1, 0, false);
    pk = __builtin_amdgcn_cvt_pk_fp8_f32(v2, v3, pk, true);
    *(unsigned*)(hrq + ((size_t)r * NN + n) * CC + c0) = (unsigned)pk;
  }
}

// Aggregation over fp8 message table: 128 B gather per edge.
// One wave per node; half-wave edge split; lane-half handles 4 channels.
__global__ __launch_bounds__(256) void aggrq_k(const int* __restrict__ off,
                                               const uint2* __restrict__ payload,
                                               const unsigned char* __restrict__ hrq,
                                               const float* __restrict__ rootsrc,
                                               const float* __restrict__ bias,
                                               ushort_t* __restrict__ xbw, int xoff) {
  int wave = threadIdx.x >> 6, lane = threadIdx.x & 63;
  int d = blockIdx.x * 4 + wave;
  if (d >= NN) return;
  int beg = off[d], end = off[d + 1];
  int half = lane >> 5, l = lane & 31;
  int c0 = l * 4;
  float a0 = 0.f, a1 = 0.f, a2 = 0.f, a3 = 0.f;
  int i = beg + half;
  for (; i + 2 < end; i += 4) {
    uint2 pA = payload[i], pB = payload[i + 2];
    unsigned uA = *(const unsigned*)(hrq + ((size_t)(pA.x >> 20) * NN + (pA.x & 0xFFFFFu)) * CC + c0);
    unsigned uB = *(const unsigned*)(hrq + ((size_t)(pB.x >> 20) * NN + (pB.x & 0xFFFFFu)) * CC + c0);
    float wA = __uint_as_float(pA.y), wB = __uint_as_float(pB.y);
    f32x2 lo = __builtin_amdgcn_cvt_pk_f32_fp8(uA, false);
    f32x2 hi = __builtin_amdgcn_cvt_pk_f32_fp8(uA, true);
    a0 += wA * lo.x; a1 += wA * lo.y; a2 += wA * hi.x; a3 += wA * hi.y;
    lo = __builtin_amdgcn_cvt_pk_f32_fp8(uB, false);
    hi = __builtin_amdgcn_cvt_pk_f32_fp8(uB, true);
    a0 += wB * lo.x; a1 += wB * lo.y; a2 += wB * hi.x; a3 += wB * hi.y;
  }
  if (i < end) {
    uint2 p = payload[i];
    unsigned u = *(const unsigned*)(hrq + ((size_t)(p.x >> 20) * NN + (p.x & 0xFFFFFu)) * CC + c0);
    float w = __uint_as_float(p.y);
    f32x2 lo = __builtin_amdgcn_cvt_pk_f32_fp8(u, false);
    f32x2 hi = __builtin_amdgcn_cvt_pk_f32_fp8(u, true);
    a0 += w * lo.x; a1 += w * lo.y; a2 += w * hi.x; a3 += w * hi.y;
  }
  a0 += __shfl_xor(a0, 32);
  a1 += __shfl_xor(a1, 32);
  a2 += __shfl_xor(a2, 32);
  a3 += __shfl_xor(a3, 32);
  if (half == 0) {
    float4 rt = *(const float4*)(rootsrc + (size_t)d * CC + c0);
    float4 bs = *(const float4*)(bias + c0);
    float v0 = fmaxf(a0 * YSI + rt.x + bs.x, 0.f);
    float v1 = fmaxf(a1 * YSI + rt.y + bs.y, 0.f);
    float v2 = fmaxf(a2 * YSI + rt.z + bs.z, 0.f);
    float v3 = fmaxf(a3 * YSI + rt.w + bs.w, 0.f);
    ushort_t pk[4] = {f2bf(v0), f2bf(v1), f2bf(v2), f2bf(v3)};
    *(uint2*)(xbw + (size_t)d * 256 + xoff + c0) = *(const uint2*)pk;
  }
}

// Layer-3 aggregation + fused relu + log_softmax over 384 cols; writes d_out.
__global__ __launch_bounds__(256) void aggrsmq_k(const int* __restrict__ off,
                                                 const uint2* __restrict__ payload,
                                                 const unsigned char* __restrict__ hrq,
                                                 const float* __restrict__ rootsrc,
                                                 const float* __restrict__ bias,
                                                 const ushort_t* __restrict__ xb,
                                                 float* __restrict__ out) {
  int wave = threadIdx.x >> 6, lane = threadIdx.x & 63;
  int d = blockIdx.x * 4 + wave;
  if (d >= NN) return;
  int beg = off[d], end = off[d + 1];
  int half = lane >> 5, l = lane & 31;
  int c0 = l * 4;
  float a0 = 0.f, a1 = 0.f, a2 = 0.f, a3 = 0.f;
  int i = beg + half;
  for (; i + 2 < end; i += 4) {
    uint2 pA = payload[i], pB = payload[i + 2];
    unsigned uA = *(const unsigned*)(hrq + ((size_t)(pA.x >> 20) * NN + (pA.x & 0xFFFFFu)) * CC + c0);
    unsigned uB = *(const unsigned*)(hrq + ((size_t)(pB.x >> 20) * NN + (pB.x & 0xFFFFFu)) * CC + c0);
    float wA = __uint_as_float(pA.y), wB = __uint_as_float(pB.y);
    f32x2 lo = __builtin_amdgcn_cvt_pk_f32_fp8(uA, false);
    f32x2 hi = __builtin_amdgcn_cvt_pk_f32_fp8(uA, true);
    a0 += wA * lo.x; a1 += wA * lo.y; a2 += wA * hi.x; a3 += wA * hi.y;
    lo = __builtin_amdgcn_cvt_pk_f32_fp8(uB, false);
    hi = __builtin_amdgcn_cvt_pk_f32_fp8(uB, true);
    a0 += wB * lo.x; a1 += wB * lo.y; a2 += wB * hi.x; a3 += wB * hi.y;
  }
  if (i < end) {
    uint2 p = payload[i];
    unsigned u = *(const unsigned*)(hrq + ((size_t)(p.x >> 20) * NN + (p.x & 0xFFFFFu)) * CC + c0);
    float w = __uint_as_float(p.y);
    f32x2 lo = __builtin_amdgcn_cvt_pk_f32_fp8(u, false);
    f32x2 hi = __builtin_amdgcn_cvt_pk_f32_fp8(u, true);
    a0 += w * lo.x; a1 += w * lo.y; a2 += w * hi.x; a3 += w * hi.y;
  }
  a0 += __shfl_xor(a0, 32);
  a1 += __shfl_xor(a1, 32);
  a2 += __shfl_xor(a2, 32);
  a3 += __shfl_xor(a3, 32);
  float4 rt = *(const float4*)(rootsrc + (size_t)d * CC + c0);
  float4 bs = *(const float4*)(bias + c0);
  float h0 = fmaxf(a0 * YSI + rt.x + bs.x, 0.f);
  float h1 = fmaxf(a1 * YSI + rt.y + bs.y, 0.f);
  float h2 = fmaxf(a2 * YSI + rt.z + bs.z, 0.f);
  float h3v = fmaxf(a3 * YSI + rt.w + bs.w, 0.f);
  float vals[6];
#pragma unroll
  for (int jj = 0; jj < 4; ++jj)
    vals[jj] = bf2f(xb[(size_t)d * 256 + jj * 64 + lane]);
  int s4 = lane >> 2, e = lane & 3;
  {
    float b0 = __shfl(h0, s4), b1 = __shfl(h1, s4), b2 = __shfl(h2, s4), b3 = __shfl(h3v, s4);
    float x01 = (e & 1) ? b1 : b0, x23 = (e & 1) ? b3 : b2;
    vals[4] = (e & 2) ? x23 : x01;
  }
  {
    int s5 = 16 + s4;
    float b0 = __shfl(h0, s5), b1 = __shfl(h1, s5), b2 = __shfl(h2, s5), b3 = __shfl(h3v, s5);
    float x01 = (e & 1) ? b1 : b0, x23 = (e & 1) ? b3 : b2;
    vals[5] = (e & 2) ? x23 : x01;
  }
  float m = vals[0];
#pragma unroll
  for (int jj = 1; jj < 6; ++jj) m = fmaxf(m, vals[jj]);
#pragma unroll
  for (int o = 32; o > 0; o >>= 1) m = fmaxf(m, __shfl_xor(m, o));
  float ssum = 0.f;
#pragma unroll
  for (int jj = 0; jj < 6; ++jj) ssum += expf(vals[jj] - m);
#pragma unroll
  for (int o = 32; o > 0; o >>= 1) ssum += __shfl_xor(ssum, o);
  float ls = logf(ssum);
#pragma unroll
  for (int jj = 0; jj < 6; ++jj)
    out[(size_t)d * H3C + jj * 64 + lane] = vals[jj] - m - ls;
}

// Fragment-major weights for 5 slots (0..3 = basis V_b [K_IN,128], 4 = root).
template <int K_IN>
__global__ void makew5_k(const float* __restrict__ basis, const float* __restrict__ root,
                         ushort_t* __restrict__ Wt) {
  int f = blockIdx.x * 256 + threadIdx.x;
  constexpr int KD = K_IN / 32;
  int tot = 5 * KD * 8 * 64;
  if (f >= tot) return;
  int l = f & 63;
  int fi = f >> 6;
  int cb = fi & 7;
  int rem = fi >> 3;
  int kk = rem & (KD - 1);
  int s = rem / KD;
  int fr = l & 15, fq = l >> 4;
  int c = cb * 16 + fr;
  int k0 = kk * 32 + fq * 8;
  ushort_t o[8];
#pragma unroll
  for (int j = 0; j < 8; ++j) {
    int k = k0 + j;
    float v = (s < 4) ? basis[((size_t)s * K_IN + k) * CC + c]
                      : root[(size_t)k * CC + c];
    o[j] = f2bf(v);
  }
  *(u16x8*)(Wt + (size_t)f * 8) = *(const u16x8*)o;
}

// y GEMM: per slot s (blockIdx.y): y_s = x @ W_s.  s<4 -> fp8*YS into yq
// (via LDS repack); s==4 -> f32 yroot.  Block 64r x 128c, 4 waves 2x2, BK=64.
template <int K_IN>
__global__ __launch_bounds__(256) void gemmy_k(const ushort_t* __restrict__ xb,
                                               const ushort_t* __restrict__ Wt,
                                               unsigned char* __restrict__ yq,
                                               float* __restrict__ yroot) {
  constexpr int NSTEPS = K_IN / 64;
  constexpr int XST = 72;
  __shared__ char smem[64 * 132 * 4];  // 33792 B; phases: (xs|wls) then repack
  ushort_t* xs = (ushort_t*)smem;                     // 64*72*2 = 9216 B
  ushort_t* wls = (ushort_t*)(smem + 64 * XST * 2);   // 16384 B
  int t = threadIdx.x;
  int wave = t >> 6, lane = t & 63;
  int wr = wave >> 1, wc = wave & 1;
  int fr = lane & 15, fq = lane >> 4;
  int row0 = blockIdx.x * 64;
  int s = blockIdx.y;
  const ushort_t* wslot = Wt + (size_t)s * (K_IN * 128);

  u16x8 areg0, areg1, breg[4];
  auto stage = [&](int step) {
    int seg = t & 7;
    int row = t >> 3;
    int gr = row0 + row;
    if (gr >= NN) gr = NN - 1;
    areg0 = *(const u16x8*)(xb + (size_t)gr * 256 + step * 64 + seg * 8);
    row = (t + 256) >> 3;
    gr = row0 + row;
    if (gr >= NN) gr = NN - 1;
    areg1 = *(const u16x8*)(xb + (size_t)gr * 256 + step * 64 + seg * 8);
    const ushort_t* bsrc = wslot + (size_t)step * 8192;
#pragma unroll
    for (int q = 0; q < 4; ++q)
      breg[q] = *(const u16x8*)(bsrc + (size_t)(t + q * 256) * 8);
  };

  f32x4 acc[2][4];
#pragma unroll
  for (int rf = 0; rf < 2; ++rf)
#pragma unroll
    for (int cb = 0; cb < 4; ++cb) acc[rf][cb] = (f32x4){0.f, 0.f, 0.f, 0.f};

  stage(0);
  for (int step = 0; step < NSTEPS; ++step) {
    __syncthreads();
    {
      int seg = t & 7;
      *(u16x8*)(xs + (t >> 3) * XST + seg * 8) = areg0;
      *(u16x8*)(xs + ((t + 256) >> 3) * XST + seg * 8) = areg1;
    }
#pragma unroll
    for (int q = 0; q < 4; ++q)
      *(u16x8*)(wls + (size_t)(t + q * 256) * 8) = breg[q];
    __syncthreads();
    if (step + 1 < NSTEPS) stage(step + 1);
#pragma unroll
    for (int kk = 0; kk < 2; ++kk) {
      bf16x8 a0 = *(const bf16x8*)(xs + (wr * 32 + fr) * XST + kk * 32 + fq * 8);
      bf16x8 a1 = *(const bf16x8*)(xs + (wr * 32 + 16 + fr) * XST + kk * 32 + fq * 8);
#pragma unroll
      for (int cb = 0; cb < 4; ++cb) {
        bf16x8 b = *(const bf16x8*)(wls + ((kk * 8 + wc * 4 + cb) * 64 + lane) * 8);
        acc[0][cb] = __builtin_amdgcn_mfma_f32_16x16x32_bf16(a0, b, acc[0][cb], 0, 0, 0);
        acc[1][cb] = __builtin_amdgcn_mfma_f32_16x16x32_bf16(a1, b, acc[1][cb], 0, 0, 0);
      }
    }
  }

  if (s == 4) {
#pragma unroll
    for (int rf = 0; rf < 2; ++rf)
#pragma unroll
      for (int cb = 0; cb < 4; ++cb) {
        int c = wc * 64 + cb * 16 + fr;
#pragma unroll
        for (int j = 0; j < 4; ++j) {
          int n = row0 + wr * 32 + rf * 16 + fq * 4 + j;
          if (n < NN) yroot[(size_t)n * CC + c] = acc[rf][cb][j];
        }
      }
  } else {
    __syncthreads();
    float* rp = (float*)smem;  // [64][132]
#pragma unroll
    for (int rf = 0; rf < 2; ++rf)
#pragma unroll
      for (int cb = 0; cb < 4; ++cb)
#pragma unroll
        for (int j = 0; j < 4; ++j)
          rp[(wr * 32 + rf * 16 + fq * 4 + j) * 132 + wc * 64 + cb * 16 + fr] = acc[rf][cb][j];
    __syncthreads();
    int row = t & 63, c0 = (t >> 6) * 32;
    int gr = row0 + row;
    if (gr < NN) {
      const float* src = rp + row * 132 + c0;
      unsigned ub[8];
#pragma unroll
      for (int q = 0; q < 8; ++q) {
        float4 v = *(const float4*)(src + q * 4);
        int pk = __builtin_amdgcn_cvt_pk_fp8_f32(v.x * YS, v.y * YS, 0, false);
        pk = __builtin_amdgcn_cvt_pk_fp8_f32(v.z * YS, v.w * YS, pk, true);
        ub[q] = (unsigned)pk;
      }
      unsigned char* dst = yq + (size_t)gr * 512 + s * 128 + c0;
      *(uint4*)dst = make_uint4(ub[0], ub[1], ub[2], ub[3]);
      *(uint4*)(dst + 16) = make_uint4(ub[4], ub[5], ub[6], ub[7]);
    }
  }
}

extern "C" void kernel_launch(void* const* d_in, const int* in_sizes, int n_in,
                              void* d_out, int out_size, void* d_ws, size_t ws_size,
                              hipStream_t stream) {
  const int* ei = (const int*)d_in[0];
  const int* et = (const int*)d_in[1];
  const float* basis1 = (const float*)d_in[2];
  const float* comp1 = (const float*)d_in[3];
  const float* root1 = (const float*)d_in[4];
  const float* bias1 = (const float*)d_in[5];
  const float* basis_b0 = (const float*)d_in[6];
  const float* comp_b0 = (const float*)d_in[7];
  const float* root_b0 = (const float*)d_in[8];
  const float* bias_b0 = (const float*)d_in[9];
  const float* basis_b1 = (const float*)d_in[10];
  const float* comp_b1 = (const float*)d_in[11];
  const float* root_b1 = (const float*)d_in[12];
  const float* bias_b1 = (const float*)d_in[13];
  float* out = (float*)d_out;  // [N][384]
  char* ws = (char*)d_ws;

  uint2* payload = (uint2*)ws;                            // 4 MB
  float* yroot = (float*)(payload + EE);                  // N*128 f32 = 25.6 MB
  ushort_t* xb = (ushort_t*)(yroot + (size_t)NN * CC);    // N*256 bf16 = 25.6 MB
  ushort_t* wt = xb + (size_t)NN * 256;                   // 327680 u16 = 0.66 MB
  unsigned char* yq = (unsigned char*)(wt + 327680);      // N*512 fp8 = 25.6 MB
  unsigned char* hrq = yq + (size_t)NN * 512;             // R*N*C fp8 = 51.2 MB
  int* cnt_rd = (int*)(hrq + (size_t)RR * NN * CC);       // R*N int
  int* cur = cnt_rd + (size_t)RR * NN;                    // N int
  int* off = cur + NN;                                    // N+1 int
  int* bsum = off + NN + 1;
  int* bbase = bsum + 256;
  size_t need = (size_t)((char*)(bbase + 256) - ws);
  if (ws_size < need) return;

  // --- CSR build ---
  zero_int_k<<<(RR * NN + NN + 255) / 256, 256, 0, stream>>>(cnt_rd, RR * NN + NN);
  count_k<<<(EE + 255) / 256, 256, 0, stream>>>(ei, et, cnt_rd);
  scanA_k<<<NB, 256, 0, stream>>>(cnt_rd, off, bsum);
  scanB_k<<<1, 256, 0, stream>>>(bsum, bbase);
  scanC_k<<<NB, 256, 0, stream>>>(off, bbase);
  fill_k<<<(EE + 255) / 256, 256, 0, stream>>>(ei, et, cnt_rd, off, cur, payload);

  const int AG_BLKS = (NN + 3) / 4;
  const int HQ_BLKS = (NN * 32 + 255) / 256;  // 6250
  const int GE_BLKS = (NN + 63) / 64;         // 782
  dim3 gy(GE_BLKS, 5);

  // --- layer 1: message table straight from basis1 ---
  makehr1q_k<<<HQ_BLKS, 256, 0, stream>>>(basis1, comp1, hrq);
  aggrq_k<<<AG_BLKS, 256, 0, stream>>>(off, payload, hrq, root1, bias1, xb, 0);

  // --- layer 2 (K=128) ---
  makew5_k<128><<<(5 * 4 * 8 * 64 + 255) / 256, 256, 0, stream>>>(basis_b0, root_b0, wt);
  gemmy_k<128><<<gy, 256, 0, stream>>>(xb, wt, yq, yroot);
  makehrq_k<<<HQ_BLKS, 256, 0, stream>>>(yq, comp_b0, hrq);
  aggrq_k<<<AG_BLKS, 256, 0, stream>>>(off, payload, hrq, yroot, bias_b0, xb, CC);

  // --- layer 3 (K=256) + fused log_softmax ---
  makew5_k<256><<<(5 * 8 * 8 * 64 + 255) / 256, 256, 0, stream>>>(basis_b1, root_b1, wt);
  gemmy_k<256><<<gy, 256, 0, stream>>>(xb, wt, yq, yroot);
  makehrq_k<<<HQ_BLKS, 256, 0, stream>>>(yq, comp_b1, hrq);
  aggrsmq_k<<<AG_BLKS, 256, 0, stream>>>(off, payload, hrq, yroot, bias_b1, xb, out);
}

// Round 10
// 274.479 us; speedup vs baseline: 1.4679x; 1.0316x over previous
//
#include <hip/hip_runtime.h>
#include <cstdint>
#include <cstddef>

#define NN 50000
#define EE 500000
#define RR 8
#define CC 128
#define BB 4
#define H3C 384
#define NB 196  // ceil(NN/256)
#define YS 64.0f
#define YSI (1.0f / 64.0f)

typedef unsigned short ushort_t;
typedef __bf16 bf16x8 __attribute__((ext_vector_type(8)));
typedef float f32x4 __attribute__((ext_vector_type(4)));
typedef float f32x2 __attribute__((ext_vector_type(2)));
typedef unsigned short u16x8 __attribute__((ext_vector_type(8)));

static __device__ __forceinline__ ushort_t f2bf(float f) {
  unsigned u = __float_as_uint(f);
  unsigned r = (u + 0x7fffu + ((u >> 16) & 1u)) >> 16;
  return (ushort_t)r;
}
static __device__ __forceinline__ float bf2f(ushort_t u) {
  return __uint_as_float(((unsigned)u) << 16);
}

// accumulate 8 fp8 channels (2 dwords) with weight w
static __device__ __forceinline__ void acc8(float* a, unsigned vx, unsigned vy, float w) {
  f32x2 t;
  t = __builtin_amdgcn_cvt_pk_f32_fp8(vx, false); a[0] += w * t.x; a[1] += w * t.y;
  t = __builtin_amdgcn_cvt_pk_f32_fp8(vx, true);  a[2] += w * t.x; a[3] += w * t.y;
  t = __builtin_amdgcn_cvt_pk_f32_fp8(vy, false); a[4] += w * t.x; a[5] += w * t.y;
  t = __builtin_amdgcn_cvt_pk_f32_fp8(vy, true);  a[6] += w * t.x; a[7] += w * t.y;
}

__global__ void zero_int_k(int* p, int n) {
  int i = blockIdx.x * 256 + threadIdx.x;
  if (i < n) p[i] = 0;
}

__global__ void count_k(const int* __restrict__ ei, const int* __restrict__ et, int* cnt) {
  int e = blockIdx.x * 256 + threadIdx.x;
  if (e >= EE) return;
  int d = ei[EE + e];
  int r = et[e];
  atomicAdd(&cnt[r * NN + d], 1);
}

__global__ __launch_bounds__(256) void scanA_k(const int* __restrict__ cnt_rd, int* off, int* bsum) {
  __shared__ int s[256];
  int t = threadIdx.x;
  int i = blockIdx.x * 256 + t;
  int v = 0;
  if (i < NN) {
#pragma unroll
    for (int r = 0; r < RR; ++r) v += cnt_rd[r * NN + i];
  }
  s[t] = v;
  __syncthreads();
  for (int d = 1; d < 256; d <<= 1) {
    int x = (t >= d) ? s[t - d] : 0;
    __syncthreads();
    s[t] += x;
    __syncthreads();
  }
  if (i < NN) off[i] = s[t] - v;
  if (t == 255) bsum[blockIdx.x] = s[255];
}

__global__ __launch_bounds__(256) void scanB_k(const int* __restrict__ bsum, int* bbase) {
  __shared__ int s[256];
  int t = threadIdx.x;
  int v = (t < NB) ? bsum[t] : 0;
  s[t] = v;
  __syncthreads();
  for (int d = 1; d < 256; d <<= 1) {
    int x = (t >= d) ? s[t - d] : 0;
    __syncthreads();
    s[t] += x;
    __syncthreads();
  }
  if (t < NB) bbase[t] = s[t] - v;
}

__global__ void scanC_k(int* off, const int* __restrict__ bbase) {
  int i = blockIdx.x * 256 + threadIdx.x;
  if (i < NN) off[i] += bbase[i >> 8];
  if (i == 0) off[NN] = EE;
}

// Scatter edges into CSR slots; payload = {src | (r<<20), bits(1/max(cnt_rd,1))}.
__global__ void fill_k(const int* __restrict__ ei, const int* __restrict__ et,
                       const int* __restrict__ cnt_rd, const int* __restrict__ off,
                       int* cur, uint2* __restrict__ payload) {
  int e = blockIdx.x * 256 + threadIdx.x;
  if (e >= EE) return;
  int s = ei[e], d = ei[EE + e], r = et[e];
  int pos = off[d] + atomicAdd(&cur[d], 1);
  float w = 1.0f / (float)max(cnt_rd[r * NN + d], 1);
  payload[pos] = make_uint2((unsigned)s | ((unsigned)r << 20), __float_as_uint(w));
}

// Layer-1 message table: hrq[r][n][c] = fp8(YS * sum_b comp1[r][b]*basis1[b][n][c])
__global__ void makehr1q_k(const float* __restrict__ basis1, const float* __restrict__ comp1,
                           unsigned char* __restrict__ hrq) {
  __shared__ float comps[RR * BB];
  if (threadIdx.x < RR * BB) comps[threadIdx.x] = comp1[threadIdx.x] * YS;
  __syncthreads();
  int idx = blockIdx.x * 256 + threadIdx.x;  // n*32 + c4
  if (idx >= NN * 32) return;
  int n = idx >> 5, c0 = (idx & 31) * 4;
  float4 y[BB];
#pragma unroll
  for (int b = 0; b < BB; ++b)
    y[b] = *(const float4*)(basis1 + ((size_t)b * NN + n) * CC + c0);
#pragma unroll
  for (int r = 0; r < RR; ++r) {
    float k0 = comps[r * BB + 0], k1 = comps[r * BB + 1];
    float k2 = comps[r * BB + 2], k3 = comps[r * BB + 3];
    float v0 = k0 * y[0].x + k1 * y[1].x + k2 * y[2].x + k3 * y[3].x;
    float v1 = k0 * y[0].y + k1 * y[1].y + k2 * y[2].y + k3 * y[3].y;
    float v2 = k0 * y[0].z + k1 * y[1].z + k2 * y[2].z + k3 * y[3].z;
    float v3 = k0 * y[0].w + k1 * y[1].w + k2 * y[2].w + k3 * y[3].w;
    int pk = __builtin_amdgcn_cvt_pk_fp8_f32(v0, v1, 0, false);
    pk = __builtin_amdgcn_cvt_pk_fp8_f32(v2, v3, pk, true);
    *(unsigned*)(hrq + ((size_t)r * NN + n) * CC + c0) = (unsigned)pk;
  }
}

// Layers 2/3 message table: hrq[r][n][c] = fp8( sum_b comp[r][b] * yq_b[n][c] )
__global__ void makehrq_k(const unsigned char* __restrict__ yq, const float* __restrict__ comp,
                          unsigned char* __restrict__ hrq) {
  __shared__ float comps[RR * BB];
  if (threadIdx.x < RR * BB) comps[threadIdx.x] = comp[threadIdx.x];
  __syncthreads();
  int idx = blockIdx.x * 256 + threadIdx.x;  // n*32 + c4
  if (idx >= NN * 32) return;
  int n = idx >> 5, c0 = (idx & 31) * 4;
  const unsigned char* yr = yq + (size_t)n * 512 + c0;
  float y[BB][4];
#pragma unroll
  for (int b = 0; b < BB; ++b) {
    unsigned u = *(const unsigned*)(yr + b * 128);
    f32x2 lo = __builtin_amdgcn_cvt_pk_f32_fp8(u, false);
    f32x2 hi = __builtin_amdgcn_cvt_pk_f32_fp8(u, true);
    y[b][0] = lo.x; y[b][1] = lo.y; y[b][2] = hi.x; y[b][3] = hi.y;
  }
#pragma unroll
  for (int r = 0; r < RR; ++r) {
    float k0 = comps[r * BB + 0], k1 = comps[r * BB + 1];
    float k2 = comps[r * BB + 2], k3 = comps[r * BB + 3];
    float v0 = k0 * y[0][0] + k1 * y[1][0] + k2 * y[2][0] + k3 * y[3][0];
    float v1 = k0 * y[0][1] + k1 * y[1][1] + k2 * y[2][1] + k3 * y[3][1];
    float v2 = k0 * y[0][2] + k1 * y[1][2] + k2 * y[2][2] + k3 * y[3][2];
    float v3 = k0 * y[0][3] + k1 * y[1][3] + k2 * y[2][3] + k3 * y[3][3];
    int pk = __builtin_amdgcn_cvt_pk_fp8_f32(v0, v1, 0, false);
    pk = __builtin_amdgcn_cvt_pk_fp8_f32(v2, v3, pk, true);
    *(unsigned*)(hrq + ((size_t)r * NN + n) * CC + c0) = (unsigned)pk;
  }
}

// Aggregation: one wave per node; 4 quarter-wave groups each own an edge
// stream (4 edges in flight); lane handles 8 channels (8B gather per edge).
template <bool ROOTF32>
__global__ __launch_bounds__(256) void aggrq_k(const int* __restrict__ off,
                                               const uint2* __restrict__ payload,
                                               const unsigned char* __restrict__ hrq,
                                               const float* __restrict__ rootf,
                                               const ushort_t* __restrict__ rootb,
                                               const float* __restrict__ bias,
                                               ushort_t* __restrict__ xbw, int xoff) {
  int wave = threadIdx.x >> 6, lane = threadIdx.x & 63;
  int d = blockIdx.x * 4 + wave;
  if (d >= NN) return;
  int beg = off[d], end = off[d + 1];
  int g = lane >> 4, q = lane & 15;
  int c0 = q * 8;
  float a[8] = {};
  int i = beg + g;
  for (; i + 4 < end; i += 8) {
    uint2 pA = payload[i], pB = payload[i + 4];
    uint2 vA = *(const uint2*)(hrq + ((size_t)(pA.x >> 20) * NN + (pA.x & 0xFFFFFu)) * CC + c0);
    uint2 vB = *(const uint2*)(hrq + ((size_t)(pB.x >> 20) * NN + (pB.x & 0xFFFFFu)) * CC + c0);
    acc8(a, vA.x, vA.y, __uint_as_float(pA.y));
    acc8(a, vB.x, vB.y, __uint_as_float(pB.y));
  }
  if (i < end) {
    uint2 p = payload[i];
    uint2 v = *(const uint2*)(hrq + ((size_t)(p.x >> 20) * NN + (p.x & 0xFFFFFu)) * CC + c0);
    acc8(a, v.x, v.y, __uint_as_float(p.y));
  }
#pragma unroll
  for (int j = 0; j < 8; ++j) {
    a[j] += __shfl_xor(a[j], 16);
    a[j] += __shfl_xor(a[j], 32);
  }
  if (g == 0) {
    float rt[8];
    if (ROOTF32) {
      float4 r0 = *(const float4*)(rootf + (size_t)d * CC + c0);
      float4 r1 = *(const float4*)(rootf + (size_t)d * CC + c0 + 4);
      rt[0] = r0.x; rt[1] = r0.y; rt[2] = r0.z; rt[3] = r0.w;
      rt[4] = r1.x; rt[5] = r1.y; rt[6] = r1.z; rt[7] = r1.w;
    } else {
      u16x8 u = *(const u16x8*)(rootb + (size_t)d * CC + c0);
#pragma unroll
      for (int j = 0; j < 8; ++j) rt[j] = bf2f((ushort_t)u[j]);
    }
    float4 b0 = *(const float4*)(bias + c0);
    float4 b1 = *(const float4*)(bias + c0 + 4);
    float bs[8] = {b0.x, b0.y, b0.z, b0.w, b1.x, b1.y, b1.z, b1.w};
    unsigned pk[4];
#pragma unroll
    for (int j = 0; j < 4; ++j) {
      float v0 = fmaxf(a[2 * j] * YSI + rt[2 * j] + bs[2 * j], 0.f);
      float v1 = fmaxf(a[2 * j + 1] * YSI + rt[2 * j + 1] + bs[2 * j + 1], 0.f);
      pk[j] = (unsigned)f2bf(v0) | ((unsigned)f2bf(v1) << 16);
    }
    *(uint4*)(xbw + (size_t)d * 256 + xoff + c0) = make_uint4(pk[0], pk[1], pk[2], pk[3]);
  }
}

// Layer-3 aggregation + fused relu + log_softmax over 384 cols; writes d_out.
__global__ __launch_bounds__(256) void aggrsmq_k(const int* __restrict__ off,
                                                 const uint2* __restrict__ payload,
                                                 const unsigned char* __restrict__ hrq,
                                                 const ushort_t* __restrict__ rootb,
                                                 const float* __restrict__ bias,
                                                 const ushort_t* __restrict__ xb,
                                                 float* __restrict__ out) {
  __shared__ float hl[4][128];
  int wave = threadIdx.x >> 6, lane = threadIdx.x & 63;
  int d = blockIdx.x * 4 + wave;
  if (d >= NN) return;
  int beg = off[d], end = off[d + 1];
  int g = lane >> 4, q = lane & 15;
  int c0 = q * 8;
  float a[8] = {};
  int i = beg + g;
  for (; i + 4 < end; i += 8) {
    uint2 pA = payload[i], pB = payload[i + 4];
    uint2 vA = *(const uint2*)(hrq + ((size_t)(pA.x >> 20) * NN + (pA.x & 0xFFFFFu)) * CC + c0);
    uint2 vB = *(const uint2*)(hrq + ((size_t)(pB.x >> 20) * NN + (pB.x & 0xFFFFFu)) * CC + c0);
    acc8(a, vA.x, vA.y, __uint_as_float(pA.y));
    acc8(a, vB.x, vB.y, __uint_as_float(pB.y));
  }
  if (i < end) {
    uint2 p = payload[i];
    uint2 v = *(const uint2*)(hrq + ((size_t)(p.x >> 20) * NN + (p.x & 0xFFFFFu)) * CC + c0);
    acc8(a, v.x, v.y, __uint_as_float(p.y));
  }
#pragma unroll
  for (int j = 0; j < 8; ++j) {
    a[j] += __shfl_xor(a[j], 16);
    a[j] += __shfl_xor(a[j], 32);
  }
  if (g == 0) {
    u16x8 u = *(const u16x8*)(rootb + (size_t)d * CC + c0);
    float4 b0 = *(const float4*)(bias + c0);
    float4 b1 = *(const float4*)(bias + c0 + 4);
    float bs[8] = {b0.x, b0.y, b0.z, b0.w, b1.x, b1.y, b1.z, b1.w};
    float h[8];
#pragma unroll
    for (int j = 0; j < 8; ++j)
      h[j] = fmaxf(a[j] * YSI + bf2f((ushort_t)u[j]) + bs[j], 0.f);
    *(f32x4*)(&hl[wave][c0]) = (f32x4){h[0], h[1], h[2], h[3]};
    *(f32x4*)(&hl[wave][c0 + 4]) = (f32x4){h[4], h[5], h[6], h[7]};
  }
  // intra-wave ds_write -> ds_read (in order); no block barrier needed
  float vals[6];
#pragma unroll
  for (int jj = 0; jj < 4; ++jj)
    vals[jj] = bf2f(xb[(size_t)d * 256 + jj * 64 + lane]);
  vals[4] = hl[wave][lane];
  vals[5] = hl[wave][64 + lane];
  float m = vals[0];
#pragma unroll
  for (int jj = 1; jj < 6; ++jj) m = fmaxf(m, vals[jj]);
#pragma unroll
  for (int o = 32; o > 0; o >>= 1) m = fmaxf(m, __shfl_xor(m, o));
  float ssum = 0.f;
#pragma unroll
  for (int jj = 0; jj < 6; ++jj) ssum += expf(vals[jj] - m);
#pragma unroll
  for (int o = 32; o > 0; o >>= 1) ssum += __shfl_xor(ssum, o);
  float ls = logf(ssum);
#pragma unroll
  for (int jj = 0; jj < 6; ++jj)
    out[(size_t)d * H3C + jj * 64 + lane] = vals[jj] - m - ls;
}

// Fragment-major weights for 5 slots (0..3 = basis V_b [K_IN,128], 4 = root).
template <int K_IN>
__global__ void makew5_k(const float* __restrict__ basis, const float* __restrict__ root,
                         ushort_t* __restrict__ Wt) {
  int f = blockIdx.x * 256 + threadIdx.x;
  constexpr int KD = K_IN / 32;
  int tot = 5 * KD * 8 * 64;
  if (f >= tot) return;
  int l = f & 63;
  int fi = f >> 6;
  int cb = fi & 7;
  int rem = fi >> 3;
  int kk = rem & (KD - 1);
  int s = rem / KD;
  int fr = l & 15, fq = l >> 4;
  int c = cb * 16 + fr;
  int k0 = kk * 32 + fq * 8;
  ushort_t o[8];
#pragma unroll
  for (int j = 0; j < 8; ++j) {
    int k = k0 + j;
    float v = (s < 4) ? basis[((size_t)s * K_IN + k) * CC + c]
                      : root[(size_t)k * CC + c];
    o[j] = f2bf(v);
  }
  *(u16x8*)(Wt + (size_t)f * 8) = *(const u16x8*)o;
}

// y GEMM: per slot s (blockIdx.y): y_s = x @ W_s.  s<4 -> fp8*YS into yq
// (via LDS repack); s==4 -> bf16 yroot.  Block 64r x 128c, 4 waves 2x2, BK=64.
template <int K_IN>
__global__ __launch_bounds__(256) void gemmy_k(const ushort_t* __restrict__ xb,
                                               const ushort_t* __restrict__ Wt,
                                               unsigned char* __restrict__ yq,
                                               ushort_t* __restrict__ yroot) {
  constexpr int NSTEPS = K_IN / 64;
  constexpr int XST = 72;
  __shared__ char smem[64 * 132 * 4];  // 33792 B; phases: (xs|wls) then repack
  ushort_t* xs = (ushort_t*)smem;                     // 64*72*2 = 9216 B
  ushort_t* wls = (ushort_t*)(smem + 64 * XST * 2);   // 16384 B
  int t = threadIdx.x;
  int wave = t >> 6, lane = t & 63;
  int wr = wave >> 1, wc = wave & 1;
  int fr = lane & 15, fq = lane >> 4;
  int row0 = blockIdx.x * 64;
  int s = blockIdx.y;
  const ushort_t* wslot = Wt + (size_t)s * (K_IN * 128);

  u16x8 areg0, areg1, breg[4];
  auto stage = [&](int step) {
    int seg = t & 7;
    int row = t >> 3;
    int gr = row0 + row;
    if (gr >= NN) gr = NN - 1;
    areg0 = *(const u16x8*)(xb + (size_t)gr * 256 + step * 64 + seg * 8);
    row = (t + 256) >> 3;
    gr = row0 + row;
    if (gr >= NN) gr = NN - 1;
    areg1 = *(const u16x8*)(xb + (size_t)gr * 256 + step * 64 + seg * 8);
    const ushort_t* bsrc = wslot + (size_t)step * 8192;
#pragma unroll
    for (int q = 0; q < 4; ++q)
      breg[q] = *(const u16x8*)(bsrc + (size_t)(t + q * 256) * 8);
  };

  f32x4 acc[2][4];
#pragma unroll
  for (int rf = 0; rf < 2; ++rf)
#pragma unroll
    for (int cb = 0; cb < 4; ++cb) acc[rf][cb] = (f32x4){0.f, 0.f, 0.f, 0.f};

  stage(0);
  for (int step = 0; step < NSTEPS; ++step) {
    __syncthreads();
    {
      int seg = t & 7;
      *(u16x8*)(xs + (t >> 3) * XST + seg * 8) = areg0;
      *(u16x8*)(xs + ((t + 256) >> 3) * XST + seg * 8) = areg1;
    }
#pragma unroll
    for (int q = 0; q < 4; ++q)
      *(u16x8*)(wls + (size_t)(t + q * 256) * 8) = breg[q];
    __syncthreads();
    if (step + 1 < NSTEPS) stage(step + 1);
#pragma unroll
    for (int kk = 0; kk < 2; ++kk) {
      bf16x8 a0 = *(const bf16x8*)(xs + (wr * 32 + fr) * XST + kk * 32 + fq * 8);
      bf16x8 a1 = *(const bf16x8*)(xs + (wr * 32 + 16 + fr) * XST + kk * 32 + fq * 8);
#pragma unroll
      for (int cb = 0; cb < 4; ++cb) {
        bf16x8 b = *(const bf16x8*)(wls + ((kk * 8 + wc * 4 + cb) * 64 + lane) * 8);
        acc[0][cb] = __builtin_amdgcn_mfma_f32_16x16x32_bf16(a0, b, acc[0][cb], 0, 0, 0);
        acc[1][cb] = __builtin_amdgcn_mfma_f32_16x16x32_bf16(a1, b, acc[1][cb], 0, 0, 0);
      }
    }
  }

  if (s == 4) {
#pragma unroll
    for (int rf = 0; rf < 2; ++rf)
#pragma unroll
      for (int cb = 0; cb < 4; ++cb) {
        int c = wc * 64 + cb * 16 + fr;
#pragma unroll
        for (int j = 0; j < 4; ++j) {
          int n = row0 + wr * 32 + rf * 16 + fq * 4 + j;
          if (n < NN) yroot[(size_t)n * CC + c] = f2bf(acc[rf][cb][j]);
        }
      }
  } else {
    __syncthreads();
    float* rp = (float*)smem;  // [64][132]
#pragma unroll
    for (int rf = 0; rf < 2; ++rf)
#pragma unroll
      for (int cb = 0; cb < 4; ++cb)
#pragma unroll
        for (int j = 0; j < 4; ++j)
          rp[(wr * 32 + rf * 16 + fq * 4 + j) * 132 + wc * 64 + cb * 16 + fr] = acc[rf][cb][j];
    __syncthreads();
    int row = t & 63, c0 = (t >> 6) * 32;
    int gr = row0 + row;
    if (gr < NN) {
      const float* src = rp + row * 132 + c0;
      unsigned ub[8];
#pragma unroll
      for (int q = 0; q < 8; ++q) {
        float4 v = *(const float4*)(src + q * 4);
        int pk = __builtin_amdgcn_cvt_pk_fp8_f32(v.x * YS, v.y * YS, 0, false);
        pk = __builtin_amdgcn_cvt_pk_fp8_f32(v.z * YS, v.w * YS, pk, true);
        ub[q] = (unsigned)pk;
      }
      unsigned char* dst = yq + (size_t)gr * 512 + s * 128 + c0;
      *(uint4*)dst = make_uint4(ub[0], ub[1], ub[2], ub[3]);
      *(uint4*)(dst + 16) = make_uint4(ub[4], ub[5], ub[6], ub[7]);
    }
  }
}

extern "C" void kernel_launch(void* const* d_in, const int* in_sizes, int n_in,
                              void* d_out, int out_size, void* d_ws, size_t ws_size,
                              hipStream_t stream) {
  const int* ei = (const int*)d_in[0];
  const int* et = (const int*)d_in[1];
  const float* basis1 = (const float*)d_in[2];
  const float* comp1 = (const float*)d_in[3];
  const float* root1 = (const float*)d_in[4];
  const float* bias1 = (const float*)d_in[5];
  const float* basis_b0 = (const float*)d_in[6];
  const float* comp_b0 = (const float*)d_in[7];
  const float* root_b0 = (const float*)d_in[8];
  const float* bias_b0 = (const float*)d_in[9];
  const float* basis_b1 = (const float*)d_in[10];
  const float* comp_b1 = (const float*)d_in[11];
  const float* root_b1 = (const float*)d_in[12];
  const float* bias_b1 = (const float*)d_in[13];
  float* out = (float*)d_out;  // [N][384]
  char* ws = (char*)d_ws;

  uint2* payload = (uint2*)ws;                            // 4 MB
  ushort_t* yroot = (ushort_t*)(payload + EE);            // N*128 bf16 = 12.8 MB
  ushort_t* xb = yroot + (size_t)NN * CC;                 // N*256 bf16 = 25.6 MB
  ushort_t* wt = xb + (size_t)NN * 256;                   // 327680 u16 = 0.66 MB
  unsigned char* yq = (unsigned char*)(wt + 327680);      // N*512 fp8 = 25.6 MB
  unsigned char* hrq = yq + (size_t)NN * 512;             // R*N*C fp8 = 51.2 MB
  int* cnt_rd = (int*)(hrq + (size_t)RR * NN * CC);       // R*N int
  int* cur = cnt_rd + (size_t)RR * NN;                    // N int
  int* off = cur + NN;                                    // N+1 int
  int* bsum = off + NN + 1;
  int* bbase = bsum + 256;
  size_t need = (size_t)((char*)(bbase + 256) - ws);
  if (ws_size < need) return;

  // --- CSR build ---
  zero_int_k<<<(RR * NN + NN + 255) / 256, 256, 0, stream>>>(cnt_rd, RR * NN + NN);
  count_k<<<(EE + 255) / 256, 256, 0, stream>>>(ei, et, cnt_rd);
  scanA_k<<<NB, 256, 0, stream>>>(cnt_rd, off, bsum);
  scanB_k<<<1, 256, 0, stream>>>(bsum, bbase);
  scanC_k<<<NB, 256, 0, stream>>>(off, bbase);
  fill_k<<<(EE + 255) / 256, 256, 0, stream>>>(ei, et, cnt_rd, off, cur, payload);

  const int AG_BLKS = (NN + 3) / 4;
  const int HQ_BLKS = (NN * 32 + 255) / 256;  // 6250
  const int GE_BLKS = (NN + 63) / 64;         // 782
  dim3 gy(GE_BLKS, 5);

  // --- layer 1: message table straight from basis1; f32 root1 ---
  makehr1q_k<<<HQ_BLKS, 256, 0, stream>>>(basis1, comp1, hrq);
  aggrq_k<true><<<AG_BLKS, 256, 0, stream>>>(off, payload, hrq, root1, nullptr, bias1, xb, 0);

  // --- layer 2 (K=128) ---
  makew5_k<128><<<(5 * 4 * 8 * 64 + 255) / 256, 256, 0, stream>>>(basis_b0, root_b0, wt);
  gemmy_k<128><<<gy, 256, 0, stream>>>(xb, wt, yq, yroot);
  makehrq_k<<<HQ_BLKS, 256, 0, stream>>>(yq, comp_b0, hrq);
  aggrq_k<false><<<AG_BLKS, 256, 0, stream>>>(off, payload, hrq, nullptr, yroot, bias_b0, xb, CC);

  // --- layer 3 (K=256) + fused log_softmax ---
  makew5_k<256><<<(5 * 8 * 8 * 64 + 255) / 256, 256, 0, stream>>>(basis_b1, root_b1, wt);
  gemmy_k<256><<<gy, 256, 0, stream>>>(xb, wt, yq, yroot);
  makehrq_k<<<HQ_BLKS, 256, 0, stream>>>(yq, comp_b1, hrq);
  aggrsmq_k<<<AG_BLKS, 256, 0, stream>>>(off, payload, hrq, yroot, bias_b1, xb, out);
}